// Round 1
// baseline (3222.963 us; speedup 1.0000x reference)
//
#include <hip/hip_runtime.h>

#define NNODES 50000
#define NEDGES 800000
#define F 128
#define NREL 8

// ---------------------------------------------------------------------------
// C[M,128] = A[M,128] @ W[128,128] (+bias). 64x64 block tile, 4x4 microtile.
// blockIdx.z selects relation: W += z*wStride, C += z*cStride.
// ---------------------------------------------------------------------------
__global__ __launch_bounds__(256)
void gemm128(const float* __restrict__ A, const float* __restrict__ W0,
             size_t wStride, float* __restrict__ C0, size_t cStride,
             const float* __restrict__ bias, int Mrows) {
  const float* Wp = W0 + (size_t)blockIdx.z * wStride;
  float* C = C0 + (size_t)blockIdx.z * cStride;
  __shared__ float As[16][64];   // [k][row]
  __shared__ float Bs[16][64];   // [k][col]
  const int tid = threadIdx.x;
  const int tx = tid & 15, ty = tid >> 4;      // 16x16 thread grid
  const int row0 = blockIdx.x * 64;
  const int col0 = blockIdx.y * 64;
  const int lrow = tid >> 2, lkq = tid & 3;    // A staging: 64 rows x 4 k-quads
  float acc[4][4] = {{0.f}};
  for (int k0 = 0; k0 < 128; k0 += 16) {
    int gr = row0 + lrow; if (gr >= Mrows) gr = Mrows - 1;   // clamp (store guarded)
    float4 av = *(const float4*)(A + (size_t)gr * F + k0 + lkq * 4);
    float4 bv = *(const float4*)(Wp + (size_t)(k0 + ty) * F + col0 + tx * 4);
    __syncthreads();
    As[lkq * 4 + 0][lrow] = av.x;
    As[lkq * 4 + 1][lrow] = av.y;
    As[lkq * 4 + 2][lrow] = av.z;
    As[lkq * 4 + 3][lrow] = av.w;
    *(float4*)&Bs[ty][tx * 4] = bv;
    __syncthreads();
#pragma unroll
    for (int kk = 0; kk < 16; ++kk) {
      float4 a4 = *(const float4*)&As[kk][ty * 4];
      float4 b4 = *(const float4*)&Bs[kk][tx * 4];
      float a[4] = {a4.x, a4.y, a4.z, a4.w};
      float b[4] = {b4.x, b4.y, b4.z, b4.w};
#pragma unroll
      for (int i = 0; i < 4; ++i)
#pragma unroll
        for (int j = 0; j < 4; ++j)
          acc[i][j] = fmaf(a[i], b[j], acc[i][j]);
    }
  }
  float4 bb = make_float4(0.f, 0.f, 0.f, 0.f);
  if (bias) bb = *(const float4*)(bias + col0 + tx * 4);
#pragma unroll
  for (int i = 0; i < 4; ++i) {
    int gr = row0 + ty * 4 + i;
    if (gr < Mrows) {
      float4 v;
      v.x = acc[i][0] + bb.x;
      v.y = acc[i][1] + bb.y;
      v.z = acc[i][2] + bb.z;
      v.w = acc[i][3] + bb.w;
      *(float4*)(C + (size_t)gr * F + col0 + tx * 4) = v;
    }
  }
}

// ---------------------------------------------------------------------------
// Per-edge gather of relation-transformed src features + atomic scatter to dst.
// 32 threads per edge, float4 each (128 floats/edge).
// relFilter < 0: xr holds all 8 relations (stride relStride).
// relFilter >= 0: xr holds one relation; skip non-matching edges.
// ---------------------------------------------------------------------------
__global__ __launch_bounds__(256)
void edge_scatter(const float* __restrict__ xr, size_t relStride, int relFilter,
                  const int* __restrict__ src, const int* __restrict__ dst,
                  const int* __restrict__ et, float* __restrict__ agg) {
  int tid = blockIdx.x * 256 + threadIdx.x;
  int e = tid >> 5;
  if (e >= NEDGES) return;
  int r = et[e];
  if (relFilter >= 0 && r != relFilter) return;
  int f4 = tid & 31;
  size_t base = (relFilter >= 0) ? 0 : (size_t)r * relStride;
  const float4* sp = (const float4*)(xr + base + (size_t)src[e] * F);
  float4 v = sp[f4];
  float* dp = agg + (size_t)dst[e] * F + (size_t)f4 * 4;
  atomicAdd(dp + 0, v.x);
  atomicAdd(dp + 1, v.y);
  atomicAdd(dp + 2, v.z);
  atomicAdd(dp + 3, v.w);
}

__global__ __launch_bounds__(256)
void relu_inplace(float* __restrict__ x, int n4) {
  int i = blockIdx.x * 256 + threadIdx.x;
  if (i < n4) {
    float4 v = ((float4*)x)[i];
    v.x = fmaxf(v.x, 0.f);
    v.y = fmaxf(v.y, 0.f);
    v.z = fmaxf(v.z, 0.f);
    v.w = fmaxf(v.w, 0.f);
    ((float4*)x)[i] = v;
  }
}

// Column sums of relu(X) -> pooled[128] (pre-zeroed), grid-strided over rows.
__global__ __launch_bounds__(128)
void colsum_relu(const float* __restrict__ X, int rows, float* __restrict__ pooled) {
  int col = threadIdx.x;
  float acc = 0.f;
  for (int r = blockIdx.x; r < rows; r += gridDim.x)
    acc += fmaxf(X[(size_t)r * F + col], 0.f);
  atomicAdd(&pooled[col], acc);
}

__global__ __launch_bounds__(128)
void final_fc(const float* __restrict__ pooled, const float* __restrict__ fc_w,
              const float* __restrict__ fc_b, float* __restrict__ out) {
  __shared__ float s[F];
  int t = threadIdx.x;
  s[t] = pooled[t] * (1.0f / (float)NNODES) * fc_w[t];
  __syncthreads();
  if (t == 0) {
    float v = 0.f;
    for (int i = 0; i < F; ++i) v += s[i];
    v += fc_b[0];
    out[0] = 1.f / (1.f + expf(-v));
  }
}

extern "C" void kernel_launch(void* const* d_in, const int* in_sizes, int n_in,
                              void* d_out, int out_size, void* d_ws, size_t ws_size,
                              hipStream_t stream) {
  const float* in_feat = (const float*)d_in[0];
  const float* W1      = (const float*)d_in[1];
  const float* W1s     = (const float*)d_in[2];
  const float* b1      = (const float*)d_in[3];
  const float* W2      = (const float*)d_in[4];
  const float* W2s     = (const float*)d_in[5];
  const float* b2      = (const float*)d_in[6];
  const float* fcw     = (const float*)d_in[7];
  const float* fcb     = (const float*)d_in[8];
  const int*   src     = (const int*)d_in[9];
  const int*   dst     = (const int*)d_in[10];
  const int*   et      = (const int*)d_in[11];
  float* out = (float*)d_out;

  const size_t eh = (size_t)NNODES * F;  // 6.4M floats
  float* ws = (float*)d_ws;
  // Full path: xr for all 8 relations (204.8MB) + h1 + h2 + pooled.
  const int chunk = (ws_size >= (10 * eh * 4 + 4096)) ? 8 : 1;
  float* xr     = ws;
  float* h1     = ws + (size_t)chunk * eh;
  float* h2     = h1 + eh;
  float* pooled = h2 + eh;

  hipMemsetAsync(pooled, 0, 256 * sizeof(float), stream);

  const int rowTiles = (NNODES + 63) / 64;   // 782
  const int scatterBlocks = (NEDGES * 32 + 255) / 256;  // 100000

  auto layer = [&](const float* h, const float* Wr, const float* Wself,
                   const float* bias, float* agg) {
    dim3 gs(rowTiles, 2, 1);
    // agg = h @ Wself + bias  (initializes agg — no zeroing needed)
    gemm128<<<gs, 256, 0, stream>>>(h, Wself, 0, agg, 0, bias, NNODES);
    if (chunk == 8) {
      dim3 g8(rowTiles, 2, 8);
      gemm128<<<g8, 256, 0, stream>>>(h, Wr, (size_t)F * F, xr, eh, nullptr, NNODES);
      edge_scatter<<<scatterBlocks, 256, 0, stream>>>(xr, eh, -1, src, dst, et, agg);
    } else {
      for (int r = 0; r < NREL; ++r) {
        gemm128<<<gs, 256, 0, stream>>>(h, Wr + (size_t)r * F * F, 0, xr, 0, nullptr, NNODES);
        edge_scatter<<<scatterBlocks, 256, 0, stream>>>(xr, 0, r, src, dst, et, agg);
      }
    }
  };

  // Layer 1
  layer(in_feat, W1, W1s, b1, h1);
  relu_inplace<<<(int)(eh / 4 + 255) / 256, 256, 0, stream>>>(h1, (int)(eh / 4));
  // Layer 2 (relu fused into pooling)
  layer(h1, W2, W2s, b2, h2);
  // Mean-pool + fc + sigmoid
  colsum_relu<<<512, 128, 0, stream>>>(h2, NNODES, pooled);
  final_fc<<<1, 128, 0, stream>>>(pooled, fcw, fcb, out);
}

// Round 2
// 842.840 us; speedup vs baseline: 3.8239x; 3.8239x over previous
//
#include <hip/hip_runtime.h>

#define NNODES 50000
#define NEDGES 800000
#define F 128
#define NREL 8
#define KPRE (NREL * F)      // 1024
#define KTOT (KPRE + F)      // 1152

// ============================ CSR build =====================================
__global__ __launch_bounds__(256)
void k_hist(const int* __restrict__ dst, int* __restrict__ deg) {
  int e = blockIdx.x * 256 + threadIdx.x;
  if (e < NEDGES) atomicAdd(&deg[dst[e]], 1);
}

__global__ __launch_bounds__(256)
void k_blocksum(const int* __restrict__ deg, int* __restrict__ partial) {
  __shared__ int s[256];
  int i = blockIdx.x * 256 + threadIdx.x;
  s[threadIdx.x] = (i < NNODES) ? deg[i] : 0;
  __syncthreads();
  for (int off = 128; off > 0; off >>= 1) {
    if (threadIdx.x < off) s[threadIdx.x] += s[threadIdx.x + off];
    __syncthreads();
  }
  if (threadIdx.x == 0) partial[blockIdx.x] = s[0];
}

__global__ __launch_bounds__(256)
void k_scanpartial(int* __restrict__ partial, int nb) {
  __shared__ int s[256];
  int t = threadIdx.x;
  int v = (t < nb) ? partial[t] : 0;
  s[t] = v;
  __syncthreads();
  for (int off = 1; off < 256; off <<= 1) {
    int x = (t >= off) ? s[t - off] : 0;
    __syncthreads();
    s[t] += x;
    __syncthreads();
  }
  if (t < nb) partial[t] = s[t] - v;  // exclusive
}

__global__ __launch_bounds__(256)
void k_scanfinal(const int* __restrict__ deg, const int* __restrict__ partial,
                 int* __restrict__ rowptr, int* __restrict__ cursor) {
  __shared__ int s[256];
  int i = blockIdx.x * 256 + threadIdx.x;
  int t = threadIdx.x;
  int v = (i < NNODES) ? deg[i] : 0;
  s[t] = v;
  __syncthreads();
  for (int off = 1; off < 256; off <<= 1) {
    int x = (t >= off) ? s[t - off] : 0;
    __syncthreads();
    s[t] += x;
    __syncthreads();
  }
  int excl = s[t] - v + partial[blockIdx.x];
  if (i < NNODES) { rowptr[i] = excl; cursor[i] = excl; }
  if (i == 0) rowptr[NNODES] = NEDGES;
}

__global__ __launch_bounds__(256)
void k_fill(const int* __restrict__ src, const int* __restrict__ dst,
            const int* __restrict__ et, int* __restrict__ cursor,
            int* __restrict__ edata) {
  int e = blockIdx.x * 256 + threadIdx.x;
  if (e >= NEDGES) return;
  int p = atomicAdd(&cursor[dst[e]], 1);
  edata[p] = (src[e] << 3) | et[e];  // src < 65536, et < 8
}

// ===================== per-dst gather of raw h (no atomics) =================
// One wave per dst node. 8 per-relation float2 accumulators in registers.
// Writes pre[n][8][128] (zeros included for empty relations).
__global__ __launch_bounds__(256)
void k_gather(const float* __restrict__ h, const int* __restrict__ rowptr,
              const int* __restrict__ edata, float* __restrict__ pre) {
  int wave = (blockIdx.x * 256 + threadIdx.x) >> 6;
  int lane = threadIdx.x & 63;
  if (wave >= NNODES) return;
  int beg = rowptr[wave], end = rowptr[wave + 1];
  float2 acc[NREL];
#pragma unroll
  for (int r = 0; r < NREL; ++r) acc[r] = make_float2(0.f, 0.f);
  for (int e = beg; e < end; ++e) {
    int packed = __builtin_amdgcn_readfirstlane(edata[e]);
    int s = packed >> 3, r = packed & 7;
    float2 v = *(const float2*)(h + (size_t)s * F + lane * 2);
#pragma unroll
    for (int rr = 0; rr < NREL; ++rr)
      if (rr == r) { acc[rr].x += v.x; acc[rr].y += v.y; }
  }
  float2* o = (float2*)(pre + (size_t)wave * KPRE) + lane;
#pragma unroll
  for (int r = 0; r < NREL; ++r) o[(size_t)r * 64] = acc[r];
}

// ============ fused GEMM: relu([pre|h] @ [Wr;Wself] + b) ====================
// A row n = concat(pre[n][0..7][:], hprev[n][:])  (K = 1152)
// outH != null: store result. pooled != null: atomic column-sum of result.
__global__ __launch_bounds__(256)
void gemm_fused(const float* __restrict__ pre, const float* __restrict__ hprev,
                const float* __restrict__ Wr, const float* __restrict__ Wself,
                const float* __restrict__ bias, float* __restrict__ outH,
                float* __restrict__ pooled) {
  __shared__ float As[16][64];
  __shared__ float Bs[16][64];
  __shared__ float Cs[16][64];
  const int tid = threadIdx.x;
  const int tx = tid & 15, ty = tid >> 4;
  const int row0 = blockIdx.x * 64;
  const int col0 = blockIdx.y * 64;
  const int lrow = tid >> 2, lkq = tid & 3;
  float acc[4][4] = {{0.f}};
  for (int k0 = 0; k0 < KTOT; k0 += 16) {
    int gr = row0 + lrow; if (gr >= NNODES) gr = NNODES - 1;
    const float* arow = (k0 < KPRE) ? (pre + (size_t)gr * KPRE + k0)
                                    : (hprev + (size_t)gr * F + (k0 - KPRE));
    float4 av = *(const float4*)(arow + lkq * 4);
    int gk = k0 + ty;
    const float* brow = (gk < KPRE) ? (Wr + (size_t)gk * F)
                                    : (Wself + (size_t)(gk - KPRE) * F);
    float4 bv = *(const float4*)(brow + col0 + tx * 4);
    __syncthreads();
    As[lkq * 4 + 0][lrow] = av.x;
    As[lkq * 4 + 1][lrow] = av.y;
    As[lkq * 4 + 2][lrow] = av.z;
    As[lkq * 4 + 3][lrow] = av.w;
    *(float4*)&Bs[ty][tx * 4] = bv;
    __syncthreads();
#pragma unroll
    for (int kk = 0; kk < 16; ++kk) {
      float4 a4 = *(const float4*)&As[kk][ty * 4];
      float4 b4 = *(const float4*)&Bs[kk][tx * 4];
      float a[4] = {a4.x, a4.y, a4.z, a4.w};
      float b[4] = {b4.x, b4.y, b4.z, b4.w};
#pragma unroll
      for (int i = 0; i < 4; ++i)
#pragma unroll
        for (int j = 0; j < 4; ++j)
          acc[i][j] = fmaf(a[i], b[j], acc[i][j]);
    }
  }
  float4 bb = *(const float4*)(bias + col0 + tx * 4);
  float cp[4] = {0.f, 0.f, 0.f, 0.f};
#pragma unroll
  for (int i = 0; i < 4; ++i) {
    int gr = row0 + ty * 4 + i;
    bool valid = gr < NNODES;
    float v[4];
    v[0] = fmaxf(acc[i][0] + bb.x, 0.f);
    v[1] = fmaxf(acc[i][1] + bb.y, 0.f);
    v[2] = fmaxf(acc[i][2] + bb.z, 0.f);
    v[3] = fmaxf(acc[i][3] + bb.w, 0.f);
    if (valid) {
      if (outH)
        *(float4*)(outH + (size_t)gr * F + col0 + tx * 4) =
            make_float4(v[0], v[1], v[2], v[3]);
      cp[0] += v[0]; cp[1] += v[1]; cp[2] += v[2]; cp[3] += v[3];
    }
  }
  if (pooled) {
    *(float4*)&Cs[ty][tx * 4] = make_float4(cp[0], cp[1], cp[2], cp[3]);
    __syncthreads();
    if (tid < 64) {
      float s = 0.f;
#pragma unroll
      for (int r = 0; r < 16; ++r) s += Cs[r][tid];
      atomicAdd(&pooled[col0 + tid], s);
    }
  }
}

__global__ __launch_bounds__(128)
void final_fc(const float* __restrict__ pooled, const float* __restrict__ fc_w,
              const float* __restrict__ fc_b, float* __restrict__ out) {
  __shared__ float s[F];
  int t = threadIdx.x;
  s[t] = pooled[t] * (1.0f / (float)NNODES) * fc_w[t];
  __syncthreads();
  if (t == 0) {
    float v = 0.f;
    for (int i = 0; i < F; ++i) v += s[i];
    v += fc_b[0];
    out[0] = 1.f / (1.f + expf(-v));
  }
}

// ============================================================================
extern "C" void kernel_launch(void* const* d_in, const int* in_sizes, int n_in,
                              void* d_out, int out_size, void* d_ws, size_t ws_size,
                              hipStream_t stream) {
  const float* in_feat = (const float*)d_in[0];
  const float* W1      = (const float*)d_in[1];
  const float* W1s     = (const float*)d_in[2];
  const float* b1      = (const float*)d_in[3];
  const float* W2      = (const float*)d_in[4];
  const float* W2s     = (const float*)d_in[5];
  const float* b2      = (const float*)d_in[6];
  const float* fcw     = (const float*)d_in[7];
  const float* fcb     = (const float*)d_in[8];
  const int*   src     = (const int*)d_in[9];
  const int*   dst     = (const int*)d_in[10];
  const int*   et      = (const int*)d_in[11];
  float* out = (float*)d_out;

  // Workspace layout (~235 MB)
  float* pre    = (float*)d_ws;                      // [NNODES][1024]
  float* h1     = pre + (size_t)NNODES * KPRE;       // [NNODES][128]
  float* pooled = h1 + (size_t)NNODES * F;           // [128] + pad
  int*   deg    = (int*)(pooled + 256);              // [NNODES]
  int*   rowptr = deg + NNODES;                      // [NNODES+1]
  int*   cursor = rowptr + NNODES + 1;               // [NNODES]
  int*   partial= cursor + NNODES;                   // [256]
  int*   edata  = partial + 256;                     // [NEDGES]

  hipMemsetAsync(deg, 0, NNODES * sizeof(int), stream);
  hipMemsetAsync(pooled, 0, 128 * sizeof(float), stream);

  const int eb = (NEDGES + 255) / 256;       // 3125
  const int nb = (NNODES + 255) / 256;       // 196

  // CSR (same for both layers)
  k_hist<<<eb, 256, 0, stream>>>(dst, deg);
  k_blocksum<<<nb, 256, 0, stream>>>(deg, partial);
  k_scanpartial<<<1, 256, 0, stream>>>(partial, nb);
  k_scanfinal<<<nb, 256, 0, stream>>>(deg, partial, rowptr, cursor);
  k_fill<<<eb, 256, 0, stream>>>(src, dst, et, cursor, edata);

  const int gatherBlocks = (NNODES * 64 + 255) / 256;  // 12500
  dim3 gemmGrid((NNODES + 63) / 64, 2);

  // Layer 1
  k_gather<<<gatherBlocks, 256, 0, stream>>>(in_feat, rowptr, edata, pre);
  gemm_fused<<<gemmGrid, 256, 0, stream>>>(pre, in_feat, W1, W1s, b1, h1, nullptr);
  // Layer 2 (ReLU + pooling fused into GEMM epilogue)
  k_gather<<<gatherBlocks, 256, 0, stream>>>(h1, rowptr, edata, pre);
  gemm_fused<<<gemmGrid, 256, 0, stream>>>(pre, h1, W2, W2s, b2, nullptr, pooled);

  final_fc<<<1, 128, 0, stream>>>(pooled, fcw, fcb, out);
}

// Round 3
// 474.394 us; speedup vs baseline: 6.7939x; 1.7767x over previous
//
#include <hip/hip_runtime.h>

#define NNODES 50000
#define NEDGES 800000
#define F 128
#define NREL 8
#define KPRE 1024
#define KTOT 1152

typedef short bf16x8 __attribute__((ext_vector_type(8)));
typedef float f32x4 __attribute__((ext_vector_type(4)));

__device__ __forceinline__ unsigned f2bf(float f) {  // RNE
  unsigned u = __float_as_uint(f);
  u += 0x7fffu + ((u >> 16) & 1u);
  return u >> 16;
}
__device__ __forceinline__ float bf2f(unsigned v) {
  return __uint_as_float(v << 16);
}

// ============================ CSR build =====================================
__global__ __launch_bounds__(256)
void k_hist(const int* __restrict__ dst, int* __restrict__ deg) {
  int e = blockIdx.x * 256 + threadIdx.x;
  if (e < NEDGES) atomicAdd(&deg[dst[e]], 1);
}

__global__ __launch_bounds__(256)
void k_blocksum(const int* __restrict__ deg, int* __restrict__ partial) {
  __shared__ int s[256];
  int i = blockIdx.x * 256 + threadIdx.x;
  s[threadIdx.x] = (i < NNODES) ? deg[i] : 0;
  __syncthreads();
  for (int off = 128; off > 0; off >>= 1) {
    if (threadIdx.x < off) s[threadIdx.x] += s[threadIdx.x + off];
    __syncthreads();
  }
  if (threadIdx.x == 0) partial[blockIdx.x] = s[0];
}

__global__ __launch_bounds__(256)
void k_scanpartial(int* __restrict__ partial, int nb) {
  __shared__ int s[256];
  int t = threadIdx.x;
  int v = (t < nb) ? partial[t] : 0;
  s[t] = v;
  __syncthreads();
  for (int off = 1; off < 256; off <<= 1) {
    int x = (t >= off) ? s[t - off] : 0;
    __syncthreads();
    s[t] += x;
    __syncthreads();
  }
  if (t < nb) partial[t] = s[t] - v;  // exclusive
}

__global__ __launch_bounds__(256)
void k_scanfinal(const int* __restrict__ deg, const int* __restrict__ partial,
                 int* __restrict__ rowptr, int* __restrict__ cursor) {
  __shared__ int s[256];
  int i = blockIdx.x * 256 + threadIdx.x;
  int t = threadIdx.x;
  int v = (i < NNODES) ? deg[i] : 0;
  s[t] = v;
  __syncthreads();
  for (int off = 1; off < 256; off <<= 1) {
    int x = (t >= off) ? s[t - off] : 0;
    __syncthreads();
    s[t] += x;
    __syncthreads();
  }
  int excl = s[t] - v + partial[blockIdx.x];
  if (i < NNODES) { rowptr[i] = excl; cursor[i] = excl; }
  if (i == 0) rowptr[NNODES] = NEDGES;
}

__global__ __launch_bounds__(256)
void k_fill(const int* __restrict__ src, const int* __restrict__ dst,
            const int* __restrict__ et, int* __restrict__ cursor,
            int* __restrict__ edata) {
  int e = blockIdx.x * 256 + threadIdx.x;
  if (e >= NEDGES) return;
  int p = atomicAdd(&cursor[dst[e]], 1);
  edata[p] = (src[e] << 3) | et[e];  // src < 65536, et < 8
}

// ======================= fp32 -> bf16 conversions ===========================
__global__ __launch_bounds__(256)
void k_cvt(const float* __restrict__ x, ushort* __restrict__ y, int n2) {
  int i = blockIdx.x * 256 + threadIdx.x;
  if (i < n2) {
    float2 v = ((const float2*)x)[i];
    ((unsigned*)y)[i] = f2bf(v.x) | (f2bf(v.y) << 16);
  }
}

// Wt[n][k] (bf16, K=1152): k<1024 -> Wr flat [k*128+n]; else Wself[(k-1024)*128+n]
__global__ __launch_bounds__(256)
void k_prepw(const float* __restrict__ Wr, const float* __restrict__ Wself,
             ushort* __restrict__ Wt) {
  int t = threadIdx.x;
  int n = t & 127;
  int k = blockIdx.x * 2 + (t >> 7);
  float v = (k < KPRE) ? Wr[(size_t)k * F + n]
                       : Wself[(size_t)(k - KPRE) * F + n];
  Wt[(size_t)n * KTOT + k] = (ushort)f2bf(v);
}

// ===================== per-dst gather (bf16, no atomics) ====================
// One wave per dst node. preA[node][k]: k<1024 per-relation sums; k>=1024 self h.
__global__ __launch_bounds__(256)
void k_gather(const ushort* __restrict__ h, const int* __restrict__ rowptr,
              const int* __restrict__ edata, ushort* __restrict__ preA) {
  int node = (blockIdx.x * 256 + threadIdx.x) >> 6;
  int lane = threadIdx.x & 63;
  if (node >= NNODES) return;
  int beg = rowptr[node], end = rowptr[node + 1];
  float2 acc[NREL];
#pragma unroll
  for (int r = 0; r < NREL; ++r) acc[r] = make_float2(0.f, 0.f);
  for (int e = beg; e < end; ++e) {
    int packed = __builtin_amdgcn_readfirstlane(edata[e]);
    unsigned v = *(const unsigned*)(h + (((size_t)(packed >> 3)) << 7) + (lane << 1));
    float x = bf2f(v & 0xffffu), y = bf2f(v >> 16);
    switch (packed & 7) {
      case 0: acc[0].x += x; acc[0].y += y; break;
      case 1: acc[1].x += x; acc[1].y += y; break;
      case 2: acc[2].x += x; acc[2].y += y; break;
      case 3: acc[3].x += x; acc[3].y += y; break;
      case 4: acc[4].x += x; acc[4].y += y; break;
      case 5: acc[5].x += x; acc[5].y += y; break;
      case 6: acc[6].x += x; acc[6].y += y; break;
      case 7: acc[7].x += x; acc[7].y += y; break;
    }
  }
  unsigned* o = (unsigned*)(preA + (size_t)node * KTOT) + lane;
#pragma unroll
  for (int r = 0; r < NREL; ++r)
    o[r * 64] = f2bf(acc[r].x) | (f2bf(acc[r].y) << 16);
  // self-loop copy
  o[8 * 64] = *((const unsigned*)(h + (size_t)node * F) + lane);
}

// ================= MFMA GEMM: relu(preA @ Wt^T + b) =========================
// C[50000,128] = A[50000,1152] @ B[1152,128]; block = 128 rows x 128 cols.
// 4 waves, each 64x64 via 4x4 frags of 16x16x32 bf16 MFMA.
__global__ __launch_bounds__(256)
void gemm_mfma(const ushort* __restrict__ preA, const ushort* __restrict__ Wt,
               const float* __restrict__ bias, ushort* __restrict__ outH,
               float* __restrict__ pooled) {
  __shared__ unsigned As[128 * 20];  // stride 20 words = 40 bf16 (balanced banks)
  __shared__ unsigned Bs[128 * 20];
  const int tid = threadIdx.x;
  const int lane = tid & 63;
  const int w = tid >> 6;
  const int i16 = lane & 15, q = lane >> 4;
  const int mbase = (w & 1) * 64, nbase = (w >> 1) * 64;
  const int row0 = blockIdx.x * 128;

  // staging assignment: thread -> (row, 16-elem half of 32-k chunk)
  const int srow = tid >> 1, shalf = tid & 1;
  int agr = row0 + srow; if (agr >= NNODES) agr = NNODES - 1;
  const ushort* aptr = preA + (size_t)agr * KTOT + shalf * 16;
  const ushort* bptr = Wt + (size_t)srow * KTOT + shalf * 16;
  unsigned* awr = &As[srow * 20 + shalf * 8];
  unsigned* bwr = &Bs[srow * 20 + shalf * 8];

  f32x4 acc[4][4];
#pragma unroll
  for (int a = 0; a < 4; ++a)
#pragma unroll
    for (int b = 0; b < 4; ++b) acc[a][b] = (f32x4)0.f;

  for (int k0 = 0; k0 < KTOT; k0 += 32) {
    uint4 a0 = *(const uint4*)(aptr + k0);
    uint4 a1 = *(const uint4*)(aptr + k0 + 8);
    uint4 b0 = *(const uint4*)(bptr + k0);
    uint4 b1 = *(const uint4*)(bptr + k0 + 8);
    __syncthreads();
    *(uint4*)awr = a0;
    *(uint4*)(awr + 4) = a1;
    *(uint4*)bwr = b0;
    *(uint4*)(bwr + 4) = b1;
    __syncthreads();
    bf16x8 af[4], bfr[4];
#pragma unroll
    for (int mi = 0; mi < 4; ++mi)
      af[mi] = *(const bf16x8*)&As[(mbase + mi * 16 + i16) * 20 + q * 4];
#pragma unroll
    for (int ni = 0; ni < 4; ++ni)
      bfr[ni] = *(const bf16x8*)&Bs[(nbase + ni * 16 + i16) * 20 + q * 4];
#pragma unroll
    for (int mi = 0; mi < 4; ++mi)
#pragma unroll
      for (int ni = 0; ni < 4; ++ni)
        acc[mi][ni] = __builtin_amdgcn_mfma_f32_16x16x32_bf16(
            af[mi], bfr[ni], acc[mi][ni], 0, 0, 0);
  }

  // Epilogue: bias + relu; store bf16 and/or column-sum pooling.
  float bb[4];
#pragma unroll
  for (int ni = 0; ni < 4; ++ni) bb[ni] = bias[nbase + ni * 16 + i16];
  float colsum[4] = {0.f, 0.f, 0.f, 0.f};
#pragma unroll
  for (int mi = 0; mi < 4; ++mi) {
    int rbase = row0 + mbase + mi * 16 + q * 4;
#pragma unroll
    for (int ni = 0; ni < 4; ++ni) {
      int col = nbase + ni * 16 + i16;
#pragma unroll
      for (int j = 0; j < 4; ++j) {
        int row = rbase + j;
        float v = fmaxf(acc[mi][ni][j] + bb[ni], 0.f);
        if (row < NNODES) {
          if (outH) outH[(size_t)row * F + col] = (ushort)f2bf(v);
          colsum[ni] += v;
        }
      }
    }
  }
  if (pooled) {
#pragma unroll
    for (int ni = 0; ni < 4; ++ni) {
      float s = colsum[ni];
      s += __shfl_xor(s, 16, 64);
      s += __shfl_xor(s, 32, 64);
      if (q == 0) atomicAdd(&pooled[nbase + ni * 16 + i16], s);
    }
  }
}

__global__ __launch_bounds__(128)
void final_fc(const float* __restrict__ pooled, const float* __restrict__ fc_w,
              const float* __restrict__ fc_b, float* __restrict__ out) {
  __shared__ float s[F];
  int t = threadIdx.x;
  s[t] = pooled[t] * (1.0f / (float)NNODES) * fc_w[t];
  __syncthreads();
  if (t == 0) {
    float v = 0.f;
    for (int i = 0; i < F; ++i) v += s[i];
    v += fc_b[0];
    out[0] = 1.f / (1.f + expf(-v));
  }
}

// ============================================================================
extern "C" void kernel_launch(void* const* d_in, const int* in_sizes, int n_in,
                              void* d_out, int out_size, void* d_ws, size_t ws_size,
                              hipStream_t stream) {
  const float* in_feat = (const float*)d_in[0];
  const float* W1      = (const float*)d_in[1];
  const float* W1s     = (const float*)d_in[2];
  const float* b1      = (const float*)d_in[3];
  const float* W2      = (const float*)d_in[4];
  const float* W2s     = (const float*)d_in[5];
  const float* b2      = (const float*)d_in[6];
  const float* fcw     = (const float*)d_in[7];
  const float* fcb     = (const float*)d_in[8];
  const int*   src     = (const int*)d_in[9];
  const int*   dst     = (const int*)d_in[10];
  const int*   et      = (const int*)d_in[11];
  float* out = (float*)d_out;

  // Workspace layout (~145 MB), all chunks 16B-aligned
  ushort* preA  = (ushort*)d_ws;                     // [50000][1152]
  ushort* feat0 = preA + (size_t)NNODES * KTOT;      // [50000][128]
  ushort* h1    = feat0 + (size_t)NNODES * F;        // [50000][128]
  ushort* Wt1   = h1 + (size_t)NNODES * F;           // [128][1152]
  ushort* Wt2   = Wt1 + (size_t)F * KTOT;            // [128][1152]
  float* pooled = (float*)(Wt2 + (size_t)F * KTOT);  // [128] + pad
  int*   deg    = (int*)(pooled + 256);
  int*   rowptr = deg + NNODES;
  int*   cursor = rowptr + NNODES + 1;
  int*   partial= cursor + NNODES;
  int*   edata  = partial + 256;

  hipMemsetAsync(deg, 0, NNODES * sizeof(int), stream);
  hipMemsetAsync(pooled, 0, 128 * sizeof(float), stream);

  const int eb = (NEDGES + 255) / 256;   // 3125
  const int nb = (NNODES + 255) / 256;   // 196

  // CSR (shared by both layers)
  k_hist<<<eb, 256, 0, stream>>>(dst, deg);
  k_blocksum<<<nb, 256, 0, stream>>>(deg, partial);
  k_scanpartial<<<1, 256, 0, stream>>>(partial, nb);
  k_scanfinal<<<nb, 256, 0, stream>>>(deg, partial, rowptr, cursor);
  k_fill<<<eb, 256, 0, stream>>>(src, dst, et, cursor, edata);

  // bf16 conversions
  k_cvt<<<(NNODES * F / 2 + 255) / 256, 256, 0, stream>>>(in_feat, feat0, NNODES * F / 2);
  k_prepw<<<KTOT / 2, 256, 0, stream>>>(W1, W1s, Wt1);
  k_prepw<<<KTOT / 2, 256, 0, stream>>>(W2, W2s, Wt2);

  const int gatherBlocks = (NNODES * 64 + 255) / 256;  // 12500
  const int gemmBlocks = (NNODES + 127) / 128;         // 391

  // Layer 1
  k_gather<<<gatherBlocks, 256, 0, stream>>>(feat0, rowptr, edata, preA);
  gemm_mfma<<<gemmBlocks, 256, 0, stream>>>(preA, Wt1, b1, h1, nullptr);
  // Layer 2 (ReLU + mean-pool fused)
  k_gather<<<gatherBlocks, 256, 0, stream>>>(h1, rowptr, edata, preA);
  gemm_mfma<<<gemmBlocks, 256, 0, stream>>>(preA, Wt2, b2, nullptr, pooled);

  final_fc<<<1, 128, 0, stream>>>(pooled, fcw, fcb, out);
}

// Round 4
// 472.934 us; speedup vs baseline: 6.8148x; 1.0031x over previous
//
#include <hip/hip_runtime.h>

#define NNODES 50000
#define NEDGES 800000
#define F 128
#define NREL 8
#define KPRE 1024
#define KTOT 1152

typedef short bf16x8 __attribute__((ext_vector_type(8)));
typedef float f32x4 __attribute__((ext_vector_type(4)));

__device__ __forceinline__ unsigned f2bf(float f) {  // RNE
  unsigned u = __float_as_uint(f);
  u += 0x7fffu + ((u >> 16) & 1u);
  return u >> 16;
}
__device__ __forceinline__ float bf2f(unsigned v) {
  return __uint_as_float(v << 16);
}

// ============================ CSR build =====================================
__global__ __launch_bounds__(256)
void k_hist(const int* __restrict__ dst, int* __restrict__ deg) {
  int e = blockIdx.x * 256 + threadIdx.x;
  if (e < NEDGES) atomicAdd(&deg[dst[e]], 1);
}

__global__ __launch_bounds__(256)
void k_blocksum(const int* __restrict__ deg, int* __restrict__ partial) {
  __shared__ int s[256];
  int i = blockIdx.x * 256 + threadIdx.x;
  s[threadIdx.x] = (i < NNODES) ? deg[i] : 0;
  __syncthreads();
  for (int off = 128; off > 0; off >>= 1) {
    if (threadIdx.x < off) s[threadIdx.x] += s[threadIdx.x + off];
    __syncthreads();
  }
  if (threadIdx.x == 0) partial[blockIdx.x] = s[0];
}

__global__ __launch_bounds__(256)
void k_scanpartial(int* __restrict__ partial, int nb) {
  __shared__ int s[256];
  int t = threadIdx.x;
  int v = (t < nb) ? partial[t] : 0;
  s[t] = v;
  __syncthreads();
  for (int off = 1; off < 256; off <<= 1) {
    int x = (t >= off) ? s[t - off] : 0;
    __syncthreads();
    s[t] += x;
    __syncthreads();
  }
  if (t < nb) partial[t] = s[t] - v;  // exclusive
}

__global__ __launch_bounds__(256)
void k_scanfinal(const int* __restrict__ deg, const int* __restrict__ partial,
                 int* __restrict__ rowptr, int* __restrict__ cursor) {
  __shared__ int s[256];
  int i = blockIdx.x * 256 + threadIdx.x;
  int t = threadIdx.x;
  int v = (i < NNODES) ? deg[i] : 0;
  s[t] = v;
  __syncthreads();
  for (int off = 1; off < 256; off <<= 1) {
    int x = (t >= off) ? s[t - off] : 0;
    __syncthreads();
    s[t] += x;
    __syncthreads();
  }
  int excl = s[t] - v + partial[blockIdx.x];
  if (i < NNODES) { rowptr[i] = excl; cursor[i] = excl; }
  if (i == 0) rowptr[NNODES] = NEDGES;
}

__global__ __launch_bounds__(256)
void k_fill(const int* __restrict__ src, const int* __restrict__ dst,
            const int* __restrict__ et, int* __restrict__ cursor,
            int* __restrict__ edata) {
  int e = blockIdx.x * 256 + threadIdx.x;
  if (e >= NEDGES) return;
  int p = atomicAdd(&cursor[dst[e]], 1);
  edata[p] = (src[e] << 3) | et[e];  // src < 65536, et < 8
}

// ======================= fp32 -> bf16 conversions ===========================
__global__ __launch_bounds__(256)
void k_cvt(const float* __restrict__ x, ushort* __restrict__ y, int n2) {
  int i = blockIdx.x * 256 + threadIdx.x;
  if (i < n2) {
    float2 v = ((const float2*)x)[i];
    ((unsigned*)y)[i] = f2bf(v.x) | (f2bf(v.y) << 16);
  }
}

// Wt[n][k] (bf16, K=1152): k<1024 -> Wr flat [k*128+n]; else Wself[(k-1024)*128+n]
__global__ __launch_bounds__(256)
void k_prepw(const float* __restrict__ Wr, const float* __restrict__ Wself,
             ushort* __restrict__ Wt) {
  int t = threadIdx.x;
  int n = t & 127;
  int k = blockIdx.x * 2 + (t >> 7);
  float v = (k < KPRE) ? Wr[(size_t)k * F + n]
                       : Wself[(size_t)(k - KPRE) * F + n];
  Wt[(size_t)n * KTOT + k] = (ushort)f2bf(v);
}

// ===================== per-dst gather (bf16, no atomics) ====================
// One wave per dst node. preA[node][k]: k<1024 per-relation sums; k>=1024 self h.
// Edge indices are preloaded 64-at-a-time into one register/lane; body is
// 4-way unrolled so 4 gather loads are in flight simultaneously.
__device__ __forceinline__ void acc_rel(float2* acc, int r, unsigned v) {
  float x = bf2f(v & 0xffffu), y = bf2f(v >> 16);
  switch (r) {
    case 0: acc[0].x += x; acc[0].y += y; break;
    case 1: acc[1].x += x; acc[1].y += y; break;
    case 2: acc[2].x += x; acc[2].y += y; break;
    case 3: acc[3].x += x; acc[3].y += y; break;
    case 4: acc[4].x += x; acc[4].y += y; break;
    case 5: acc[5].x += x; acc[5].y += y; break;
    case 6: acc[6].x += x; acc[6].y += y; break;
    case 7: acc[7].x += x; acc[7].y += y; break;
  }
}

__global__ __launch_bounds__(256)
void k_gather(const ushort* __restrict__ h, const int* __restrict__ rowptr,
              const int* __restrict__ edata, ushort* __restrict__ preA) {
  int node = (blockIdx.x * 256 + threadIdx.x) >> 6;
  int lane = threadIdx.x & 63;
  if (node >= NNODES) return;
  int beg = rowptr[node], end = rowptr[node + 1];
  float2 acc[NREL];
#pragma unroll
  for (int r = 0; r < NREL; ++r) acc[r] = make_float2(0.f, 0.f);

  const unsigned laneoff = lane << 1;
  for (int base = beg; base < end; base += 64) {
    int cnt = end - base; if (cnt > 64) cnt = 64;
    int my = (base + lane < end) ? edata[base + lane] : 0;  // one load / 64 edges
    int e = 0;
    for (; e + 4 <= cnt; e += 4) {
      int p0 = __builtin_amdgcn_readlane(my, e);
      int p1 = __builtin_amdgcn_readlane(my, e + 1);
      int p2 = __builtin_amdgcn_readlane(my, e + 2);
      int p3 = __builtin_amdgcn_readlane(my, e + 3);
      unsigned v0 = *(const unsigned*)(h + (((size_t)(p0 >> 3)) << 7) + laneoff);
      unsigned v1 = *(const unsigned*)(h + (((size_t)(p1 >> 3)) << 7) + laneoff);
      unsigned v2 = *(const unsigned*)(h + (((size_t)(p2 >> 3)) << 7) + laneoff);
      unsigned v3 = *(const unsigned*)(h + (((size_t)(p3 >> 3)) << 7) + laneoff);
      acc_rel(acc, p0 & 7, v0);
      acc_rel(acc, p1 & 7, v1);
      acc_rel(acc, p2 & 7, v2);
      acc_rel(acc, p3 & 7, v3);
    }
    for (; e < cnt; ++e) {
      int p = __builtin_amdgcn_readlane(my, e);
      unsigned v = *(const unsigned*)(h + (((size_t)(p >> 3)) << 7) + laneoff);
      acc_rel(acc, p & 7, v);
    }
  }

  unsigned* o = (unsigned*)(preA + (size_t)node * KTOT) + lane;
#pragma unroll
  for (int r = 0; r < NREL; ++r)
    o[r * 64] = f2bf(acc[r].x) | (f2bf(acc[r].y) << 16);
  // self-loop copy
  o[8 * 64] = *((const unsigned*)(h + (size_t)node * F) + lane);
}

// ================= MFMA GEMM: relu(preA @ Wt^T + b) =========================
// C[50000,128] = A[50000,1152] @ B[1152,128]; block = 128 rows x 128 cols.
// 4 waves, each 64x64 via 4x4 frags of 16x16x32 bf16 MFMA.
// Software-pipelined: global loads for chunk k+1 issue before chunk k's MFMAs.
__global__ __launch_bounds__(256)
void gemm_mfma(const ushort* __restrict__ preA, const ushort* __restrict__ Wt,
               const float* __restrict__ bias, ushort* __restrict__ outH,
               float* __restrict__ pooled) {
  __shared__ unsigned As[128 * 20];  // stride 20 words = 40 bf16
  __shared__ unsigned Bs[128 * 20];
  const int tid = threadIdx.x;
  const int lane = tid & 63;
  const int w = tid >> 6;
  const int i16 = lane & 15, q = lane >> 4;
  const int mbase = (w & 1) * 64, nbase = (w >> 1) * 64;
  const int row0 = blockIdx.x * 128;

  const int srow = tid >> 1, shalf = tid & 1;
  int agr = row0 + srow; if (agr >= NNODES) agr = NNODES - 1;
  const ushort* aptr = preA + (size_t)agr * KTOT + shalf * 16;
  const ushort* bptr = Wt + (size_t)srow * KTOT + shalf * 16;
  unsigned* awr = &As[srow * 20 + shalf * 8];
  unsigned* bwr = &Bs[srow * 20 + shalf * 8];

  f32x4 acc[4][4];
#pragma unroll
  for (int a = 0; a < 4; ++a)
#pragma unroll
    for (int b = 0; b < 4; ++b) acc[a][b] = (f32x4)0.f;

  uint4 pa0 = *(const uint4*)(aptr);
  uint4 pa1 = *(const uint4*)(aptr + 8);
  uint4 pb0 = *(const uint4*)(bptr);
  uint4 pb1 = *(const uint4*)(bptr + 8);

  for (int k0 = 0; k0 < KTOT; k0 += 32) {
    __syncthreads();
    *(uint4*)awr = pa0;
    *(uint4*)(awr + 4) = pa1;
    *(uint4*)bwr = pb0;
    *(uint4*)(bwr + 4) = pb1;
    __syncthreads();
    if (k0 + 32 < KTOT) {  // prefetch next chunk; latency hidden by MFMAs below
      pa0 = *(const uint4*)(aptr + k0 + 32);
      pa1 = *(const uint4*)(aptr + k0 + 40);
      pb0 = *(const uint4*)(bptr + k0 + 32);
      pb1 = *(const uint4*)(bptr + k0 + 40);
    }
    bf16x8 af[4], bfr[4];
#pragma unroll
    for (int mi = 0; mi < 4; ++mi)
      af[mi] = *(const bf16x8*)&As[(mbase + mi * 16 + i16) * 20 + q * 4];
#pragma unroll
    for (int ni = 0; ni < 4; ++ni)
      bfr[ni] = *(const bf16x8*)&Bs[(nbase + ni * 16 + i16) * 20 + q * 4];
#pragma unroll
    for (int mi = 0; mi < 4; ++mi)
#pragma unroll
      for (int ni = 0; ni < 4; ++ni)
        acc[mi][ni] = __builtin_amdgcn_mfma_f32_16x16x32_bf16(
            af[mi], bfr[ni], acc[mi][ni], 0, 0, 0);
  }

  // Epilogue: bias + relu; store bf16 and/or column-sum pooling.
  float bb[4];
#pragma unroll
  for (int ni = 0; ni < 4; ++ni) bb[ni] = bias[nbase + ni * 16 + i16];
  float colsum[4] = {0.f, 0.f, 0.f, 0.f};
#pragma unroll
  for (int mi = 0; mi < 4; ++mi) {
    int rbase = row0 + mbase + mi * 16 + q * 4;
#pragma unroll
    for (int ni = 0; ni < 4; ++ni) {
      int col = nbase + ni * 16 + i16;
#pragma unroll
      for (int j = 0; j < 4; ++j) {
        int row = rbase + j;
        float v = fmaxf(acc[mi][ni][j] + bb[ni], 0.f);
        if (row < NNODES) {
          if (outH) outH[(size_t)row * F + col] = (ushort)f2bf(v);
          colsum[ni] += v;
        }
      }
    }
  }
  if (pooled) {
#pragma unroll
    for (int ni = 0; ni < 4; ++ni) {
      float s = colsum[ni];
      s += __shfl_xor(s, 16, 64);
      s += __shfl_xor(s, 32, 64);
      if (q == 0) atomicAdd(&pooled[nbase + ni * 16 + i16], s);
    }
  }
}

__global__ __launch_bounds__(128)
void final_fc(const float* __restrict__ pooled, const float* __restrict__ fc_w,
              const float* __restrict__ fc_b, float* __restrict__ out) {
  __shared__ float s[F];
  int t = threadIdx.x;
  s[t] = pooled[t] * (1.0f / (float)NNODES) * fc_w[t];
  __syncthreads();
  if (t == 0) {
    float v = 0.f;
    for (int i = 0; i < F; ++i) v += s[i];
    v += fc_b[0];
    out[0] = 1.f / (1.f + expf(-v));
  }
}

// ============================================================================
extern "C" void kernel_launch(void* const* d_in, const int* in_sizes, int n_in,
                              void* d_out, int out_size, void* d_ws, size_t ws_size,
                              hipStream_t stream) {
  const float* in_feat = (const float*)d_in[0];
  const float* W1      = (const float*)d_in[1];
  const float* W1s     = (const float*)d_in[2];
  const float* b1      = (const float*)d_in[3];
  const float* W2      = (const float*)d_in[4];
  const float* W2s     = (const float*)d_in[5];
  const float* b2      = (const float*)d_in[6];
  const float* fcw     = (const float*)d_in[7];
  const float* fcb     = (const float*)d_in[8];
  const int*   src     = (const int*)d_in[9];
  const int*   dst     = (const int*)d_in[10];
  const int*   et      = (const int*)d_in[11];
  float* out = (float*)d_out;

  // Workspace layout (~145 MB), all chunks 16B-aligned
  ushort* preA  = (ushort*)d_ws;                     // [50000][1152]
  ushort* feat0 = preA + (size_t)NNODES * KTOT;      // [50000][128]
  ushort* h1    = feat0 + (size_t)NNODES * F;        // [50000][128]
  ushort* Wt1   = h1 + (size_t)NNODES * F;           // [128][1152]
  ushort* Wt2   = Wt1 + (size_t)F * KTOT;            // [128][1152]
  float* pooled = (float*)(Wt2 + (size_t)F * KTOT);  // [128] + pad
  int*   deg    = (int*)(pooled + 256);
  int*   rowptr = deg + NNODES;
  int*   cursor = rowptr + NNODES + 1;
  int*   partial= cursor + NNODES;
  int*   edata  = partial + 256;

  hipMemsetAsync(deg, 0, NNODES * sizeof(int), stream);
  hipMemsetAsync(pooled, 0, 128 * sizeof(float), stream);

  const int eb = (NEDGES + 255) / 256;   // 3125
  const int nb = (NNODES + 255) / 256;   // 196

  // CSR (shared by both layers)
  k_hist<<<eb, 256, 0, stream>>>(dst, deg);
  k_blocksum<<<nb, 256, 0, stream>>>(deg, partial);
  k_scanpartial<<<1, 256, 0, stream>>>(partial, nb);
  k_scanfinal<<<nb, 256, 0, stream>>>(deg, partial, rowptr, cursor);
  k_fill<<<eb, 256, 0, stream>>>(src, dst, et, cursor, edata);

  // bf16 conversions
  k_cvt<<<(NNODES * F / 2 + 255) / 256, 256, 0, stream>>>(in_feat, feat0, NNODES * F / 2);
  k_prepw<<<KTOT / 2, 256, 0, stream>>>(W1, W1s, Wt1);
  k_prepw<<<KTOT / 2, 256, 0, stream>>>(W2, W2s, Wt2);

  const int gatherBlocks = (NNODES * 64 + 255) / 256;  // 12500
  const int gemmBlocks = (NNODES + 127) / 128;         // 391

  // Layer 1
  k_gather<<<gatherBlocks, 256, 0, stream>>>(feat0, rowptr, edata, preA);
  gemm_mfma<<<gemmBlocks, 256, 0, stream>>>(preA, Wt1, b1, h1, nullptr);
  // Layer 2 (ReLU + mean-pool fused)
  k_gather<<<gatherBlocks, 256, 0, stream>>>(h1, rowptr, edata, preA);
  gemm_mfma<<<gemmBlocks, 256, 0, stream>>>(preA, Wt2, b2, nullptr, pooled);

  final_fc<<<1, 128, 0, stream>>>(pooled, fcw, fcb, out);
}

// Round 5
// 418.157 us; speedup vs baseline: 7.7075x; 1.1310x over previous
//
#include <hip/hip_runtime.h>

#define NNODES 50000
#define NEDGES 800000
#define F 128
#define NREL 8
#define NOUT 1152   // 9*128: 8 relations + self-loop

typedef short bf16x8 __attribute__((ext_vector_type(8)));
typedef float f32x4 __attribute__((ext_vector_type(4)));

__device__ __forceinline__ unsigned f2bf(float f) {  // RNE
  unsigned u = __float_as_uint(f);
  u += 0x7fffu + ((u >> 16) & 1u);
  return u >> 16;
}
__device__ __forceinline__ float bf2f(unsigned v) {
  return __uint_as_float(v << 16);
}

// ============================ CSR build =====================================
__global__ __launch_bounds__(256)
void k_hist(const int* __restrict__ dst, int* __restrict__ deg) {
  int e = blockIdx.x * 256 + threadIdx.x;
  if (e < NEDGES) atomicAdd(&deg[dst[e]], 1);
}

__global__ __launch_bounds__(256)
void k_blocksum(const int* __restrict__ deg, int* __restrict__ partial) {
  __shared__ int s[256];
  int i = blockIdx.x * 256 + threadIdx.x;
  s[threadIdx.x] = (i < NNODES) ? deg[i] : 0;
  __syncthreads();
  for (int off = 128; off > 0; off >>= 1) {
    if (threadIdx.x < off) s[threadIdx.x] += s[threadIdx.x + off];
    __syncthreads();
  }
  if (threadIdx.x == 0) partial[blockIdx.x] = s[0];
}

__global__ __launch_bounds__(256)
void k_scanpartial(int* __restrict__ partial, int nb) {
  __shared__ int s[256];
  int t = threadIdx.x;
  int v = (t < nb) ? partial[t] : 0;
  s[t] = v;
  __syncthreads();
  for (int off = 1; off < 256; off <<= 1) {
    int x = (t >= off) ? s[t - off] : 0;
    __syncthreads();
    s[t] += x;
    __syncthreads();
  }
  if (t < nb) partial[t] = s[t] - v;  // exclusive
}

__global__ __launch_bounds__(256)
void k_scanfinal(const int* __restrict__ deg, const int* __restrict__ partial,
                 int* __restrict__ rowptr, int* __restrict__ cursor) {
  __shared__ int s[256];
  int i = blockIdx.x * 256 + threadIdx.x;
  int t = threadIdx.x;
  int v = (i < NNODES) ? deg[i] : 0;
  s[t] = v;
  __syncthreads();
  for (int off = 1; off < 256; off <<= 1) {
    int x = (t >= off) ? s[t - off] : 0;
    __syncthreads();
    s[t] += x;
    __syncthreads();
  }
  int excl = s[t] - v + partial[blockIdx.x];
  if (i < NNODES) { rowptr[i] = excl; cursor[i] = excl; }
  if (i == 0) rowptr[NNODES] = NEDGES;
}

// edata[p] = element offset of the edge's message row in xrs
__global__ __launch_bounds__(256)
void k_fill(const int* __restrict__ src, const int* __restrict__ dst,
            const int* __restrict__ et, int* __restrict__ cursor,
            int* __restrict__ edata) {
  int e = blockIdx.x * 256 + threadIdx.x;
  if (e >= NEDGES) return;
  int p = atomicAdd(&cursor[dst[e]], 1);
  edata[p] = src[e] * NOUT + et[e] * F;
}

// ======================= fp32 -> bf16 conversions ===========================
__global__ __launch_bounds__(256)
void k_cvt(const float* __restrict__ x, ushort* __restrict__ y, int n2) {
  int i = blockIdx.x * 256 + threadIdx.x;
  if (i < n2) {
    float2 v = ((const float2*)x)[i];
    ((unsigned*)y)[i] = f2bf(v.x) | (f2bf(v.y) << 16);
  }
}

// Wt[n][k] bf16, n in [0,1152), k in [0,128):
//   n<1024: W_r[k][c] with r=n>>7, c=n&127;  n>=1024: Wself[k][c]
__global__ __launch_bounds__(256)
void k_prepw(const float* __restrict__ Wr, const float* __restrict__ Wself,
             ushort* __restrict__ Wt) {
  int idx = blockIdx.x * 256 + threadIdx.x;  // n*128 + k
  if (idx >= NOUT * F) return;
  int n = idx >> 7, k = idx & 127;
  int r = n >> 7, c = n & 127;
  float v = (r < NREL) ? Wr[((size_t)r * F + k) * F + c] : Wself[(size_t)k * F + c];
  Wt[idx] = (ushort)f2bf(v);
}

// ====== GEMM: xrs[50000][1152] = A[50000][128] @ Wt^T  (bf16 MFMA) ==========
// Block: 128 rows x 128 cols (blockIdx.y = column block 0..8).
// 4 waves, each 64x64 via 4x4 frags of 16x16x32; K=128 in 4 chunks of 32.
__global__ __launch_bounds__(256)
void gemm_xrs(const ushort* __restrict__ A, const ushort* __restrict__ Wt,
              ushort* __restrict__ xrs) {
  __shared__ unsigned As[128 * 20];  // 32-k chunk, stride 20 words/row
  __shared__ unsigned Bs[128 * 20];
  const int tid = threadIdx.x;
  const int lane = tid & 63;
  const int w = tid >> 6;
  const int i16 = lane & 15, q = lane >> 4;
  const int mbase = (w & 1) * 64, nbase = (w >> 1) * 64;
  const int row0 = blockIdx.x * 128;
  const int cb = blockIdx.y;

  const int srow = tid >> 1, shalf = tid & 1;
  int agr = row0 + srow; if (agr >= NNODES) agr = NNODES - 1;
  const ushort* aptr = A + (size_t)agr * F + shalf * 16;
  const ushort* bptr = Wt + ((size_t)cb * 128 + srow) * F + shalf * 16;
  unsigned* awr = &As[srow * 20 + shalf * 8];
  unsigned* bwr = &Bs[srow * 20 + shalf * 8];

  f32x4 acc[4][4];
#pragma unroll
  for (int a = 0; a < 4; ++a)
#pragma unroll
    for (int b = 0; b < 4; ++b) acc[a][b] = (f32x4)0.f;

  uint4 pa0 = *(const uint4*)(aptr);
  uint4 pa1 = *(const uint4*)(aptr + 8);
  uint4 pb0 = *(const uint4*)(bptr);
  uint4 pb1 = *(const uint4*)(bptr + 8);

#pragma unroll
  for (int k0 = 0; k0 < F; k0 += 32) {
    __syncthreads();
    *(uint4*)awr = pa0;
    *(uint4*)(awr + 4) = pa1;
    *(uint4*)bwr = pb0;
    *(uint4*)(bwr + 4) = pb1;
    __syncthreads();
    if (k0 + 32 < F) {  // prefetch next chunk
      pa0 = *(const uint4*)(aptr + k0 + 32);
      pa1 = *(const uint4*)(aptr + k0 + 40);
      pb0 = *(const uint4*)(bptr + k0 + 32);
      pb1 = *(const uint4*)(bptr + k0 + 40);
    }
    bf16x8 af[4], bfr[4];
#pragma unroll
    for (int mi = 0; mi < 4; ++mi)
      af[mi] = *(const bf16x8*)&As[(mbase + mi * 16 + i16) * 20 + q * 4];
#pragma unroll
    for (int ni = 0; ni < 4; ++ni)
      bfr[ni] = *(const bf16x8*)&Bs[(nbase + ni * 16 + i16) * 20 + q * 4];
#pragma unroll
    for (int mi = 0; mi < 4; ++mi)
#pragma unroll
      for (int ni = 0; ni < 4; ++ni)
        acc[mi][ni] = __builtin_amdgcn_mfma_f32_16x16x32_bf16(
            af[mi], bfr[ni], acc[mi][ni], 0, 0, 0);
  }

  // Store bf16 to xrs[row][cb*128 + col]
#pragma unroll
  for (int mi = 0; mi < 4; ++mi) {
    int rbase = row0 + mbase + mi * 16 + q * 4;
#pragma unroll
    for (int ni = 0; ni < 4; ++ni) {
      int col = cb * 128 + nbase + ni * 16 + i16;
#pragma unroll
      for (int j = 0; j < 4; ++j) {
        int row = rbase + j;
        if (row < NNODES)
          xrs[(size_t)row * NOUT + col] = (ushort)f2bf(acc[mi][ni][j]);
      }
    }
  }
}

// ========== aggregate: h_next[dst] = relu(sum_e xrs[edata] + self + b) ======
// One wave per dst node, single float2 accumulator, 8 loads in flight.
__global__ __launch_bounds__(256)
void k_aggregate(const ushort* __restrict__ xrs, const int* __restrict__ rowptr,
                 const int* __restrict__ edata, const float* __restrict__ bias,
                 ushort* __restrict__ hout) {
  int node = (blockIdx.x * 256 + threadIdx.x) >> 6;
  int lane = threadIdx.x & 63;
  if (node >= NNODES) return;
  int beg = rowptr[node], end = rowptr[node + 1];

  // self-loop row (r=8)
  unsigned sv = ((const unsigned*)(xrs + (size_t)node * NOUT + NREL * F))[lane];
  float ax = bf2f(sv & 0xffffu), ay = bf2f(sv >> 16);

  for (int base = beg; base < end; base += 64) {
    int cnt = end - base; if (cnt > 64) cnt = 64;
    int my = (base + lane < end) ? edata[base + lane] : 0;
    int e = 0;
    for (; e + 8 <= cnt; e += 8) {
      unsigned v0 = ((const unsigned*)(xrs + (size_t)__builtin_amdgcn_readlane(my, e + 0)))[lane];
      unsigned v1 = ((const unsigned*)(xrs + (size_t)__builtin_amdgcn_readlane(my, e + 1)))[lane];
      unsigned v2 = ((const unsigned*)(xrs + (size_t)__builtin_amdgcn_readlane(my, e + 2)))[lane];
      unsigned v3 = ((const unsigned*)(xrs + (size_t)__builtin_amdgcn_readlane(my, e + 3)))[lane];
      unsigned v4 = ((const unsigned*)(xrs + (size_t)__builtin_amdgcn_readlane(my, e + 4)))[lane];
      unsigned v5 = ((const unsigned*)(xrs + (size_t)__builtin_amdgcn_readlane(my, e + 5)))[lane];
      unsigned v6 = ((const unsigned*)(xrs + (size_t)__builtin_amdgcn_readlane(my, e + 6)))[lane];
      unsigned v7 = ((const unsigned*)(xrs + (size_t)__builtin_amdgcn_readlane(my, e + 7)))[lane];
      ax += bf2f(v0 & 0xffffu); ay += bf2f(v0 >> 16);
      ax += bf2f(v1 & 0xffffu); ay += bf2f(v1 >> 16);
      ax += bf2f(v2 & 0xffffu); ay += bf2f(v2 >> 16);
      ax += bf2f(v3 & 0xffffu); ay += bf2f(v3 >> 16);
      ax += bf2f(v4 & 0xffffu); ay += bf2f(v4 >> 16);
      ax += bf2f(v5 & 0xffffu); ay += bf2f(v5 >> 16);
      ax += bf2f(v6 & 0xffffu); ay += bf2f(v6 >> 16);
      ax += bf2f(v7 & 0xffffu); ay += bf2f(v7 >> 16);
    }
    for (; e < cnt; ++e) {
      unsigned v = ((const unsigned*)(xrs + (size_t)__builtin_amdgcn_readlane(my, e)))[lane];
      ax += bf2f(v & 0xffffu); ay += bf2f(v >> 16);
    }
  }

  float2 bb = ((const float2*)bias)[lane];
  ax = fmaxf(ax + bb.x, 0.f);
  ay = fmaxf(ay + bb.y, 0.f);
  ((unsigned*)(hout + (size_t)node * F))[lane] = f2bf(ax) | (f2bf(ay) << 16);
}

// ==================== mean-pool (+final fc) =================================
__global__ __launch_bounds__(256)
void k_colsum(const ushort* __restrict__ h2, float* __restrict__ pooled) {
  int j = threadIdx.x & 63;  // uint column (2 bf16 cols)
  float sx = 0.f, sy = 0.f;
  for (int r = blockIdx.x * 4 + (threadIdx.x >> 6); r < NNODES; r += gridDim.x * 4) {
    unsigned v = ((const unsigned*)h2)[(size_t)r * 64 + j];
    sx += bf2f(v & 0xffffu);
    sy += bf2f(v >> 16);
  }
  atomicAdd(&pooled[2 * j], sx);
  atomicAdd(&pooled[2 * j + 1], sy);
}

__global__ __launch_bounds__(128)
void final_fc(const float* __restrict__ pooled, const float* __restrict__ fc_w,
              const float* __restrict__ fc_b, float* __restrict__ out) {
  __shared__ float s[F];
  int t = threadIdx.x;
  s[t] = pooled[t] * (1.0f / (float)NNODES) * fc_w[t];
  __syncthreads();
  if (t == 0) {
    float v = 0.f;
    for (int i = 0; i < F; ++i) v += s[i];
    v += fc_b[0];
    out[0] = 1.f / (1.f + expf(-v));
  }
}

// ============================================================================
extern "C" void kernel_launch(void* const* d_in, const int* in_sizes, int n_in,
                              void* d_out, int out_size, void* d_ws, size_t ws_size,
                              hipStream_t stream) {
  const float* in_feat = (const float*)d_in[0];
  const float* W1      = (const float*)d_in[1];
  const float* W1s     = (const float*)d_in[2];
  const float* b1      = (const float*)d_in[3];
  const float* W2      = (const float*)d_in[4];
  const float* W2s     = (const float*)d_in[5];
  const float* b2      = (const float*)d_in[6];
  const float* fcw     = (const float*)d_in[7];
  const float* fcb     = (const float*)d_in[8];
  const int*   src     = (const int*)d_in[9];
  const int*   dst     = (const int*)d_in[10];
  const int*   et      = (const int*)d_in[11];
  float* out = (float*)d_out;

  // Workspace (~160 MB)
  ushort* xrs   = (ushort*)d_ws;                     // [50000][1152]
  ushort* feat0 = xrs + (size_t)NNODES * NOUT;       // [50000][128]
  ushort* h1    = feat0 + (size_t)NNODES * F;        // [50000][128]
  ushort* h2    = h1 + (size_t)NNODES * F;           // [50000][128]
  ushort* Wt1   = h2 + (size_t)NNODES * F;           // [1152][128]
  ushort* Wt2   = Wt1 + (size_t)NOUT * F;            // [1152][128]
  float* pooled = (float*)(Wt2 + (size_t)NOUT * F);  // [128] + pad
  int*   deg    = (int*)(pooled + 256);
  int*   rowptr = deg + NNODES;
  int*   cursor = rowptr + NNODES + 1;
  int*   partial= cursor + NNODES;
  int*   edata  = partial + 256;

  hipMemsetAsync(deg, 0, NNODES * sizeof(int), stream);
  hipMemsetAsync(pooled, 0, 128 * sizeof(float), stream);

  const int eb = (NEDGES + 255) / 256;   // 3125
  const int nb = (NNODES + 255) / 256;   // 196

  // CSR (shared by both layers)
  k_hist<<<eb, 256, 0, stream>>>(dst, deg);
  k_blocksum<<<nb, 256, 0, stream>>>(deg, partial);
  k_scanpartial<<<1, 256, 0, stream>>>(partial, nb);
  k_scanfinal<<<nb, 256, 0, stream>>>(deg, partial, rowptr, cursor);
  k_fill<<<eb, 256, 0, stream>>>(src, dst, et, cursor, edata);

  // bf16 conversions / weight prep
  k_cvt<<<(NNODES * F / 2 + 255) / 256, 256, 0, stream>>>(in_feat, feat0, NNODES * F / 2);
  k_prepw<<<(NOUT * F + 255) / 256, 256, 0, stream>>>(W1, W1s, Wt1);
  k_prepw<<<(NOUT * F + 255) / 256, 256, 0, stream>>>(W2, W2s, Wt2);

  dim3 gemmGrid((NNODES + 127) / 128, 9);              // 391 x 9
  const int aggBlocks = (NNODES * 64 + 255) / 256;     // 12500

  // Layer 1: transform then aggregate
  gemm_xrs<<<gemmGrid, 256, 0, stream>>>(feat0, Wt1, xrs);
  k_aggregate<<<aggBlocks, 256, 0, stream>>>(xrs, rowptr, edata, b1, h1);
  // Layer 2
  gemm_xrs<<<gemmGrid, 256, 0, stream>>>(h1, Wt2, xrs);
  k_aggregate<<<aggBlocks, 256, 0, stream>>>(xrs, rowptr, edata, b2, h2);

  // Mean-pool + fc + sigmoid
  k_colsum<<<256, 256, 0, stream>>>(h2, pooled);
  final_fc<<<1, 128, 0, stream>>>(pooled, fcw, fcb, out);
}

// Round 6
// 384.730 us; speedup vs baseline: 8.3772x; 1.0869x over previous
//
#include <hip/hip_runtime.h>

#define NNODES 50000
#define NEDGES 800000
#define F 128
#define NREL 8
#define NOUT 1152   // 9*128: 8 relations + self-loop

typedef short bf16x8 __attribute__((ext_vector_type(8)));
typedef float f32x4 __attribute__((ext_vector_type(4)));

__device__ __forceinline__ unsigned f2bf(float f) {  // RNE
  unsigned u = __float_as_uint(f);
  u += 0x7fffu + ((u >> 16) & 1u);
  return u >> 16;
}
__device__ __forceinline__ float bf2f(unsigned v) {
  return __uint_as_float(v << 16);
}

// ============================ CSR build =====================================
__global__ __launch_bounds__(256)
void k_hist(const int* __restrict__ dst, int* __restrict__ deg) {
  int e = blockIdx.x * 256 + threadIdx.x;
  if (e < NEDGES) atomicAdd(&deg[dst[e]], 1);
}

__global__ __launch_bounds__(256)
void k_blocksum(const int* __restrict__ deg, int* __restrict__ partial) {
  __shared__ int s[256];
  int i = blockIdx.x * 256 + threadIdx.x;
  s[threadIdx.x] = (i < NNODES) ? deg[i] : 0;
  __syncthreads();
  for (int off = 128; off > 0; off >>= 1) {
    if (threadIdx.x < off) s[threadIdx.x] += s[threadIdx.x + off];
    __syncthreads();
  }
  if (threadIdx.x == 0) partial[blockIdx.x] = s[0];
}

__global__ __launch_bounds__(256)
void k_scanpartial(int* __restrict__ partial, int nb) {
  __shared__ int s[256];
  int t = threadIdx.x;
  int v = (t < nb) ? partial[t] : 0;
  s[t] = v;
  __syncthreads();
  for (int off = 1; off < 256; off <<= 1) {
    int x = (t >= off) ? s[t - off] : 0;
    __syncthreads();
    s[t] += x;
    __syncthreads();
  }
  if (t < nb) partial[t] = s[t] - v;  // exclusive
}

__global__ __launch_bounds__(256)
void k_scanfinal(const int* __restrict__ deg, const int* __restrict__ partial,
                 int* __restrict__ rowptr, int* __restrict__ cursor) {
  __shared__ int s[256];
  int i = blockIdx.x * 256 + threadIdx.x;
  int t = threadIdx.x;
  int v = (i < NNODES) ? deg[i] : 0;
  s[t] = v;
  __syncthreads();
  for (int off = 1; off < 256; off <<= 1) {
    int x = (t >= off) ? s[t - off] : 0;
    __syncthreads();
    s[t] += x;
    __syncthreads();
  }
  int excl = s[t] - v + partial[blockIdx.x];
  if (i < NNODES) { rowptr[i] = excl; cursor[i] = excl; }
  if (i == 0) rowptr[NNODES] = NEDGES;
}

// edata[p] = element offset of the edge's message row in xrs
__global__ __launch_bounds__(256)
void k_fill(const int* __restrict__ src, const int* __restrict__ dst,
            const int* __restrict__ et, int* __restrict__ cursor,
            int* __restrict__ edata) {
  int e = blockIdx.x * 256 + threadIdx.x;
  if (e >= NEDGES) return;
  int p = atomicAdd(&cursor[dst[e]], 1);
  edata[p] = src[e] * NOUT + et[e] * F;
}

// ======================= fp32 -> bf16 conversions ===========================
__global__ __launch_bounds__(256)
void k_cvt(const float* __restrict__ x, ushort* __restrict__ y, int n2) {
  int i = blockIdx.x * 256 + threadIdx.x;
  if (i < n2) {
    float2 v = ((const float2*)x)[i];
    ((unsigned*)y)[i] = f2bf(v.x) | (f2bf(v.y) << 16);
  }
}

// Wt[n][k] bf16, n in [0,1152), k in [0,128):
//   n<1024: W_r[k][c] with r=n>>7, c=n&127;  n>=1024: Wself[k][c]
__global__ __launch_bounds__(256)
void k_prepw(const float* __restrict__ Wr, const float* __restrict__ Wself,
             ushort* __restrict__ Wt) {
  int idx = blockIdx.x * 256 + threadIdx.x;  // n*128 + k
  if (idx >= NOUT * F) return;
  int n = idx >> 7, k = idx & 127;
  int r = n >> 7, c = n & 127;
  float v = (r < NREL) ? Wr[((size_t)r * F + k) * F + c] : Wself[(size_t)k * F + c];
  Wt[idx] = (ushort)f2bf(v);
}

// ====== GEMM: xrs[50000][1152] = A[50000][128] @ Wt^T  (bf16 MFMA) ==========
// Block: 128 rows x 128 cols (blockIdx.y = column block 0..8).
// 4 waves, each 64x64 via 4x4 frags of 16x16x32; K=128 in 4 chunks of 32.
__global__ __launch_bounds__(256)
void gemm_xrs(const ushort* __restrict__ A, const ushort* __restrict__ Wt,
              ushort* __restrict__ xrs) {
  __shared__ unsigned As[128 * 20];  // 32-k chunk, stride 20 words/row
  __shared__ unsigned Bs[128 * 20];
  const int tid = threadIdx.x;
  const int lane = tid & 63;
  const int w = tid >> 6;
  const int i16 = lane & 15, q = lane >> 4;
  const int mbase = (w & 1) * 64, nbase = (w >> 1) * 64;
  const int row0 = blockIdx.x * 128;
  const int cb = blockIdx.y;

  const int srow = tid >> 1, shalf = tid & 1;
  int agr = row0 + srow; if (agr >= NNODES) agr = NNODES - 1;
  const ushort* aptr = A + (size_t)agr * F + shalf * 16;
  const ushort* bptr = Wt + ((size_t)cb * 128 + srow) * F + shalf * 16;
  unsigned* awr = &As[srow * 20 + shalf * 8];
  unsigned* bwr = &Bs[srow * 20 + shalf * 8];

  f32x4 acc[4][4];
#pragma unroll
  for (int a = 0; a < 4; ++a)
#pragma unroll
    for (int b = 0; b < 4; ++b) acc[a][b] = (f32x4)0.f;

  uint4 pa0 = *(const uint4*)(aptr);
  uint4 pa1 = *(const uint4*)(aptr + 8);
  uint4 pb0 = *(const uint4*)(bptr);
  uint4 pb1 = *(const uint4*)(bptr + 8);

#pragma unroll
  for (int k0 = 0; k0 < F; k0 += 32) {
    __syncthreads();
    *(uint4*)awr = pa0;
    *(uint4*)(awr + 4) = pa1;
    *(uint4*)bwr = pb0;
    *(uint4*)(bwr + 4) = pb1;
    __syncthreads();
    if (k0 + 32 < F) {  // prefetch next chunk
      pa0 = *(const uint4*)(aptr + k0 + 32);
      pa1 = *(const uint4*)(aptr + k0 + 40);
      pb0 = *(const uint4*)(bptr + k0 + 32);
      pb1 = *(const uint4*)(bptr + k0 + 40);
    }
    bf16x8 af[4], bfr[4];
#pragma unroll
    for (int mi = 0; mi < 4; ++mi)
      af[mi] = *(const bf16x8*)&As[(mbase + mi * 16 + i16) * 20 + q * 4];
#pragma unroll
    for (int ni = 0; ni < 4; ++ni)
      bfr[ni] = *(const bf16x8*)&Bs[(nbase + ni * 16 + i16) * 20 + q * 4];
#pragma unroll
    for (int mi = 0; mi < 4; ++mi)
#pragma unroll
      for (int ni = 0; ni < 4; ++ni)
        acc[mi][ni] = __builtin_amdgcn_mfma_f32_16x16x32_bf16(
            af[mi], bfr[ni], acc[mi][ni], 0, 0, 0);
  }

  // Store bf16 to xrs[row][cb*128 + col]
#pragma unroll
  for (int mi = 0; mi < 4; ++mi) {
    int rbase = row0 + mbase + mi * 16 + q * 4;
#pragma unroll
    for (int ni = 0; ni < 4; ++ni) {
      int col = cb * 128 + nbase + ni * 16 + i16;
#pragma unroll
      for (int j = 0; j < 4; ++j) {
        int row = rbase + j;
        if (row < NNODES)
          xrs[(size_t)row * NOUT + col] = (ushort)f2bf(acc[mi][ni][j]);
      }
    }
  }
}

// ========== aggregate: h_next[dst] = relu(sum_e xrs[edata] + self + b) ======
// One wave per dst node, single float2 accumulator, 8 loads in flight.
__global__ __launch_bounds__(256)
void k_aggregate(const ushort* __restrict__ xrs, const int* __restrict__ rowptr,
                 const int* __restrict__ edata, const float* __restrict__ bias,
                 ushort* __restrict__ hout) {
  int node = (blockIdx.x * 256 + threadIdx.x) >> 6;
  int lane = threadIdx.x & 63;
  if (node >= NNODES) return;
  int beg = rowptr[node], end = rowptr[node + 1];

  // self-loop row (r=8)
  unsigned sv = ((const unsigned*)(xrs + (size_t)node * NOUT + NREL * F))[lane];
  float ax = bf2f(sv & 0xffffu), ay = bf2f(sv >> 16);

  for (int base = beg; base < end; base += 64) {
    int cnt = end - base; if (cnt > 64) cnt = 64;
    int my = (base + lane < end) ? edata[base + lane] : 0;
    int e = 0;
    for (; e + 8 <= cnt; e += 8) {
      unsigned v0 = ((const unsigned*)(xrs + (size_t)__builtin_amdgcn_readlane(my, e + 0)))[lane];
      unsigned v1 = ((const unsigned*)(xrs + (size_t)__builtin_amdgcn_readlane(my, e + 1)))[lane];
      unsigned v2 = ((const unsigned*)(xrs + (size_t)__builtin_amdgcn_readlane(my, e + 2)))[lane];
      unsigned v3 = ((const unsigned*)(xrs + (size_t)__builtin_amdgcn_readlane(my, e + 3)))[lane];
      unsigned v4 = ((const unsigned*)(xrs + (size_t)__builtin_amdgcn_readlane(my, e + 4)))[lane];
      unsigned v5 = ((const unsigned*)(xrs + (size_t)__builtin_amdgcn_readlane(my, e + 5)))[lane];
      unsigned v6 = ((const unsigned*)(xrs + (size_t)__builtin_amdgcn_readlane(my, e + 6)))[lane];
      unsigned v7 = ((const unsigned*)(xrs + (size_t)__builtin_amdgcn_readlane(my, e + 7)))[lane];
      ax += bf2f(v0 & 0xffffu); ay += bf2f(v0 >> 16);
      ax += bf2f(v1 & 0xffffu); ay += bf2f(v1 >> 16);
      ax += bf2f(v2 & 0xffffu); ay += bf2f(v2 >> 16);
      ax += bf2f(v3 & 0xffffu); ay += bf2f(v3 >> 16);
      ax += bf2f(v4 & 0xffffu); ay += bf2f(v4 >> 16);
      ax += bf2f(v5 & 0xffffu); ay += bf2f(v5 >> 16);
      ax += bf2f(v6 & 0xffffu); ay += bf2f(v6 >> 16);
      ax += bf2f(v7 & 0xffffu); ay += bf2f(v7 >> 16);
    }
    for (; e < cnt; ++e) {
      unsigned v = ((const unsigned*)(xrs + (size_t)__builtin_amdgcn_readlane(my, e)))[lane];
      ax += bf2f(v & 0xffffu); ay += bf2f(v >> 16);
    }
  }

  float2 bb = ((const float2*)bias)[lane];
  ax = fmaxf(ax + bb.x, 0.f);
  ay = fmaxf(ay + bb.y, 0.f);
  ((unsigned*)(hout + (size_t)node * F))[lane] = f2bf(ax) | (f2bf(ay) << 16);
}

// ==================== mean-pool (+final fc) =================================
// 784 blocks; each wave does 4 rows/iter (4 loads in flight), ~4 iterations.
// Block-level LDS reduction -> 128 atomics per block.
__global__ __launch_bounds__(256)
void k_colsum(const ushort* __restrict__ h2, float* __restrict__ pooled) {
  __shared__ float red[4][128];
  const int j = threadIdx.x & 63;   // uint column (2 bf16 cols)
  const int wv = threadIdx.x >> 6;  // wave id 0..3
  float sx = 0.f, sy = 0.f;
  for (int r0 = blockIdx.x * 16 + wv * 4; r0 < NNODES; r0 += gridDim.x * 16) {
    const unsigned* p = (const unsigned*)h2 + (size_t)r0 * 64 + j;
    unsigned v0 = p[0];
    unsigned v1 = (r0 + 1 < NNODES) ? p[64] : 0;
    unsigned v2 = (r0 + 2 < NNODES) ? p[128] : 0;
    unsigned v3 = (r0 + 3 < NNODES) ? p[192] : 0;
    sx += bf2f(v0 & 0xffffu) + bf2f(v1 & 0xffffu) +
          bf2f(v2 & 0xffffu) + bf2f(v3 & 0xffffu);
    sy += bf2f(v0 >> 16) + bf2f(v1 >> 16) + bf2f(v2 >> 16) + bf2f(v3 >> 16);
  }
  red[wv][2 * j] = sx;
  red[wv][2 * j + 1] = sy;
  __syncthreads();
  if (threadIdx.x < 128) {
    float s = red[0][threadIdx.x] + red[1][threadIdx.x] +
              red[2][threadIdx.x] + red[3][threadIdx.x];
    atomicAdd(&pooled[threadIdx.x], s);
  }
}

__global__ __launch_bounds__(128)
void final_fc(const float* __restrict__ pooled, const float* __restrict__ fc_w,
              const float* __restrict__ fc_b, float* __restrict__ out) {
  __shared__ float s[F];
  int t = threadIdx.x;
  s[t] = pooled[t] * (1.0f / (float)NNODES) * fc_w[t];
  __syncthreads();
  if (t == 0) {
    float v = 0.f;
    for (int i = 0; i < F; ++i) v += s[i];
    v += fc_b[0];
    out[0] = 1.f / (1.f + expf(-v));
  }
}

// ============================================================================
extern "C" void kernel_launch(void* const* d_in, const int* in_sizes, int n_in,
                              void* d_out, int out_size, void* d_ws, size_t ws_size,
                              hipStream_t stream) {
  const float* in_feat = (const float*)d_in[0];
  const float* W1      = (const float*)d_in[1];
  const float* W1s     = (const float*)d_in[2];
  const float* b1      = (const float*)d_in[3];
  const float* W2      = (const float*)d_in[4];
  const float* W2s     = (const float*)d_in[5];
  const float* b2      = (const float*)d_in[6];
  const float* fcw     = (const float*)d_in[7];
  const float* fcb     = (const float*)d_in[8];
  const int*   src     = (const int*)d_in[9];
  const int*   dst     = (const int*)d_in[10];
  const int*   et      = (const int*)d_in[11];
  float* out = (float*)d_out;

  // Workspace (~160 MB)
  ushort* xrs   = (ushort*)d_ws;                     // [50000][1152]
  ushort* feat0 = xrs + (size_t)NNODES * NOUT;       // [50000][128]
  ushort* h1    = feat0 + (size_t)NNODES * F;        // [50000][128]
  ushort* h2    = h1 + (size_t)NNODES * F;           // [50000][128]
  ushort* Wt1   = h2 + (size_t)NNODES * F;           // [1152][128]
  ushort* Wt2   = Wt1 + (size_t)NOUT * F;            // [1152][128]
  float* pooled = (float*)(Wt2 + (size_t)NOUT * F);  // [128] + pad
  int*   deg    = (int*)(pooled + 256);
  int*   rowptr = deg + NNODES;
  int*   cursor = rowptr + NNODES + 1;
  int*   partial= cursor + NNODES;
  int*   edata  = partial + 256;

  hipMemsetAsync(deg, 0, NNODES * sizeof(int), stream);
  hipMemsetAsync(pooled, 0, 128 * sizeof(float), stream);

  const int eb = (NEDGES + 255) / 256;   // 3125
  const int nb = (NNODES + 255) / 256;   // 196

  // CSR (shared by both layers)
  k_hist<<<eb, 256, 0, stream>>>(dst, deg);
  k_blocksum<<<nb, 256, 0, stream>>>(deg, partial);
  k_scanpartial<<<1, 256, 0, stream>>>(partial, nb);
  k_scanfinal<<<nb, 256, 0, stream>>>(deg, partial, rowptr, cursor);
  k_fill<<<eb, 256, 0, stream>>>(src, dst, et, cursor, edata);

  // bf16 conversions / weight prep
  k_cvt<<<(NNODES * F / 2 + 255) / 256, 256, 0, stream>>>(in_feat, feat0, NNODES * F / 2);
  k_prepw<<<(NOUT * F + 255) / 256, 256, 0, stream>>>(W1, W1s, Wt1);
  k_prepw<<<(NOUT * F + 255) / 256, 256, 0, stream>>>(W2, W2s, Wt2);

  dim3 gemmGrid((NNODES + 127) / 128, 9);              // 391 x 9
  const int aggBlocks = (NNODES * 64 + 255) / 256;     // 12500

  // Layer 1: transform then aggregate
  gemm_xrs<<<gemmGrid, 256, 0, stream>>>(feat0, Wt1, xrs);
  k_aggregate<<<aggBlocks, 256, 0, stream>>>(xrs, rowptr, edata, b1, h1);
  // Layer 2
  gemm_xrs<<<gemmGrid, 256, 0, stream>>>(h1, Wt2, xrs);
  k_aggregate<<<aggBlocks, 256, 0, stream>>>(xrs, rowptr, edata, b2, h2);

  // Mean-pool + fc + sigmoid
  k_colsum<<<784, 256, 0, stream>>>(h2, pooled);
  final_fc<<<1, 128, 0, stream>>>(pooled, fcw, fcb, out);
}

// Round 7
// 339.294 us; speedup vs baseline: 9.4990x; 1.1339x over previous
//
#include <hip/hip_runtime.h>

#define NNODES 50000
#define NEDGES 800000
#define F 128
#define NREL 8
#define NOUT 1152   // 9*128: 8 relations + self-loop
#define NBKT 98     // ceil(50000 / 512) coarse buckets
#define BSH 9       // 512 nodes per bucket

typedef short bf16x8 __attribute__((ext_vector_type(8)));
typedef float f32x4 __attribute__((ext_vector_type(4)));

__device__ __forceinline__ unsigned f2bf(float f) {  // RNE
  unsigned u = __float_as_uint(f);
  u += 0x7fffu + ((u >> 16) & 1u);
  return u >> 16;
}
__device__ __forceinline__ float bf2f(unsigned v) {
  return __uint_as_float(v << 16);
}

// ================= CSR build via two-level counting sort ====================
// Phase A1: coarse histogram (dst >> 9), LDS-staged.
__global__ __launch_bounds__(256)
void k_chist(const int* __restrict__ dst, int* __restrict__ bcnt) {
  __shared__ int hist[NBKT];
  int t = threadIdx.x;
  if (t < NBKT) hist[t] = 0;
  __syncthreads();
  int e0 = blockIdx.x * 4096;
#pragma unroll
  for (int i = 0; i < 16; ++i) {
    int e = e0 + t + i * 256;
    if (e < NEDGES) atomicAdd(&hist[dst[e] >> BSH], 1);
  }
  __syncthreads();
  if (t < NBKT && hist[t] > 0) atomicAdd(&bcnt[t], hist[t]);
}

// Phase A2: exclusive scan of 98 bucket counts -> bbase, bcur.
__global__ __launch_bounds__(128)
void k_cscan(const int* __restrict__ bcnt, int* __restrict__ bbase,
             int* __restrict__ bcur, int* __restrict__ rowptr) {
  __shared__ int s[128];
  int t = threadIdx.x;
  int v = (t < NBKT) ? bcnt[t] : 0;
  s[t] = v;
  __syncthreads();
  for (int off = 1; off < 128; off <<= 1) {
    int x = (t >= off) ? s[t - off] : 0;
    __syncthreads();
    s[t] += x;
    __syncthreads();
  }
  if (t < NBKT) { bbase[t] = s[t] - v; bcur[t] = s[t] - v; }
  if (t == 0) rowptr[NNODES] = NEDGES;
}

// Phase A3: scatter packed records into coarse buckets.
// record = (dst_local << 19) | (src << 3) | et
__global__ __launch_bounds__(256)
void k_cscatter(const int* __restrict__ src, const int* __restrict__ dst,
                const int* __restrict__ et, int* __restrict__ bcur,
                int* __restrict__ ebuf) {
  __shared__ int lhist[NBKT];
  __shared__ int lbase[NBKT];
  int t = threadIdx.x;
  if (t < NBKT) lhist[t] = 0;
  __syncthreads();
  int e0 = blockIdx.x * 4096;
  int rec[16], cc[16], lr[16];
#pragma unroll
  for (int i = 0; i < 16; ++i) {
    int e = e0 + t + i * 256;
    if (e < NEDGES) {
      int d = dst[e];
      cc[i] = d >> BSH;
      rec[i] = ((d & 511) << 19) | (src[e] << 3) | et[e];
      lr[i] = atomicAdd(&lhist[cc[i]], 1);
    } else {
      cc[i] = -1;
    }
  }
  __syncthreads();
  if (t < NBKT && lhist[t] > 0) lbase[t] = atomicAdd(&bcur[t], lhist[t]);
  __syncthreads();
#pragma unroll
  for (int i = 0; i < 16; ++i)
    if (cc[i] >= 0) ebuf[lbase[cc[i]] + lr[i]] = rec[i];
}

// Phase B: per-bucket fine counting sort (one block per bucket).
// Writes rowptr (coalesced) and final edata (block-local region).
__global__ __launch_bounds__(256)
void k_fsort(const int* __restrict__ ebuf, const int* __restrict__ bbase,
             const int* __restrict__ bcnt, int* __restrict__ rowptr,
             int* __restrict__ edata) {
  __shared__ int cnt[512];
  __shared__ int pos[512];
  __shared__ int ws2[256];
  const int b = blockIdx.x, t = threadIdx.x;
  const int beg = bbase[b], end = beg + bcnt[b];
  cnt[t] = 0; cnt[t + 256] = 0;
  __syncthreads();
  // pass 1: histogram of local dst
  for (int e = beg + t; e < end; e += 256)
    atomicAdd(&cnt[((unsigned)ebuf[e]) >> 19], 1);
  __syncthreads();
  // exclusive scan of 512 via pairwise + Hillis-Steele over 256
  int a = cnt[2 * t], b2 = cnt[2 * t + 1];
  ws2[t] = a + b2;
  __syncthreads();
  for (int off = 1; off < 256; off <<= 1) {
    int x = (t >= off) ? ws2[t - off] : 0;
    __syncthreads();
    ws2[t] += x;
    __syncthreads();
  }
  int ep = ws2[t] - (a + b2);
  pos[2 * t] = ep;
  pos[2 * t + 1] = ep + a;
  __syncthreads();
  // rowptr (coalesced)
  int node0 = b << BSH;
#pragma unroll
  for (int i = t; i < 512; i += 256) {
    int node = node0 + i;
    if (node < NNODES) rowptr[node] = beg + pos[i];
  }
  __syncthreads();
  // pass 2: placement; all writes land in this block's [beg,end) region
  for (int e = beg + t; e < end; e += 256) {
    int rec = ebuf[e];
    int c = ((unsigned)rec) >> 19;
    int lrank = atomicAdd(&pos[c], 1);
    int srcv = (rec >> 3) & 0xFFFF;
    int etv = rec & 7;
    edata[beg + lrank] = srcv * NOUT + etv * F;
  }
}

// ======================= fp32 -> bf16 conversions ===========================
__global__ __launch_bounds__(256)
void k_cvt(const float* __restrict__ x, ushort* __restrict__ y, int n2) {
  int i = blockIdx.x * 256 + threadIdx.x;
  if (i < n2) {
    float2 v = ((const float2*)x)[i];
    ((unsigned*)y)[i] = f2bf(v.x) | (f2bf(v.y) << 16);
  }
}

// Wt[n][k] bf16, n in [0,1152), k in [0,128):
//   n<1024: W_r[k][c] with r=n>>7, c=n&127;  n>=1024: Wself[k][c]
__global__ __launch_bounds__(256)
void k_prepw(const float* __restrict__ Wr, const float* __restrict__ Wself,
             ushort* __restrict__ Wt) {
  int idx = blockIdx.x * 256 + threadIdx.x;  // n*128 + k
  if (idx >= NOUT * F) return;
  int n = idx >> 7, k = idx & 127;
  int r = n >> 7, c = n & 127;
  float v = (r < NREL) ? Wr[((size_t)r * F + k) * F + c] : Wself[(size_t)k * F + c];
  Wt[idx] = (ushort)f2bf(v);
}

// ====== GEMM: xrs[50000][1152] = A[50000][128] @ Wt^T  (bf16 MFMA) ==========
__global__ __launch_bounds__(256)
void gemm_xrs(const ushort* __restrict__ A, const ushort* __restrict__ Wt,
              ushort* __restrict__ xrs) {
  __shared__ unsigned As[128 * 20];
  __shared__ unsigned Bs[128 * 20];
  const int tid = threadIdx.x;
  const int lane = tid & 63;
  const int w = tid >> 6;
  const int i16 = lane & 15, q = lane >> 4;
  const int mbase = (w & 1) * 64, nbase = (w >> 1) * 64;
  const int row0 = blockIdx.x * 128;
  const int cb = blockIdx.y;

  const int srow = tid >> 1, shalf = tid & 1;
  int agr = row0 + srow; if (agr >= NNODES) agr = NNODES - 1;
  const ushort* aptr = A + (size_t)agr * F + shalf * 16;
  const ushort* bptr = Wt + ((size_t)cb * 128 + srow) * F + shalf * 16;
  unsigned* awr = &As[srow * 20 + shalf * 8];
  unsigned* bwr = &Bs[srow * 20 + shalf * 8];

  f32x4 acc[4][4];
#pragma unroll
  for (int a = 0; a < 4; ++a)
#pragma unroll
    for (int b = 0; b < 4; ++b) acc[a][b] = (f32x4)0.f;

  uint4 pa0 = *(const uint4*)(aptr);
  uint4 pa1 = *(const uint4*)(aptr + 8);
  uint4 pb0 = *(const uint4*)(bptr);
  uint4 pb1 = *(const uint4*)(bptr + 8);

#pragma unroll
  for (int k0 = 0; k0 < F; k0 += 32) {
    __syncthreads();
    *(uint4*)awr = pa0;
    *(uint4*)(awr + 4) = pa1;
    *(uint4*)bwr = pb0;
    *(uint4*)(bwr + 4) = pb1;
    __syncthreads();
    if (k0 + 32 < F) {
      pa0 = *(const uint4*)(aptr + k0 + 32);
      pa1 = *(const uint4*)(aptr + k0 + 40);
      pb0 = *(const uint4*)(bptr + k0 + 32);
      pb1 = *(const uint4*)(bptr + k0 + 40);
    }
    bf16x8 af[4], bfr[4];
#pragma unroll
    for (int mi = 0; mi < 4; ++mi)
      af[mi] = *(const bf16x8*)&As[(mbase + mi * 16 + i16) * 20 + q * 4];
#pragma unroll
    for (int ni = 0; ni < 4; ++ni)
      bfr[ni] = *(const bf16x8*)&Bs[(nbase + ni * 16 + i16) * 20 + q * 4];
#pragma unroll
    for (int mi = 0; mi < 4; ++mi)
#pragma unroll
      for (int ni = 0; ni < 4; ++ni)
        acc[mi][ni] = __builtin_amdgcn_mfma_f32_16x16x32_bf16(
            af[mi], bfr[ni], acc[mi][ni], 0, 0, 0);
  }

#pragma unroll
  for (int mi = 0; mi < 4; ++mi) {
    int rbase = row0 + mbase + mi * 16 + q * 4;
#pragma unroll
    for (int ni = 0; ni < 4; ++ni) {
      int col = cb * 128 + nbase + ni * 16 + i16;
#pragma unroll
      for (int j = 0; j < 4; ++j) {
        int row = rbase + j;
        if (row < NNODES)
          xrs[(size_t)row * NOUT + col] = (ushort)f2bf(acc[mi][ni][j]);
      }
    }
  }
}

// ========== aggregate: h_next[dst] = relu(sum_e xrs[edata] + self + b) ======
__global__ __launch_bounds__(256)
void k_aggregate(const ushort* __restrict__ xrs, const int* __restrict__ rowptr,
                 const int* __restrict__ edata, const float* __restrict__ bias,
                 ushort* __restrict__ hout) {
  int node = (blockIdx.x * 256 + threadIdx.x) >> 6;
  int lane = threadIdx.x & 63;
  if (node >= NNODES) return;
  int beg = rowptr[node], end = rowptr[node + 1];

  unsigned sv = ((const unsigned*)(xrs + (size_t)node * NOUT + NREL * F))[lane];
  float ax = bf2f(sv & 0xffffu), ay = bf2f(sv >> 16);

  for (int base = beg; base < end; base += 64) {
    int cnt = end - base; if (cnt > 64) cnt = 64;
    int my = (base + lane < end) ? edata[base + lane] : 0;
    int e = 0;
    for (; e + 8 <= cnt; e += 8) {
      unsigned v0 = ((const unsigned*)(xrs + (size_t)__builtin_amdgcn_readlane(my, e + 0)))[lane];
      unsigned v1 = ((const unsigned*)(xrs + (size_t)__builtin_amdgcn_readlane(my, e + 1)))[lane];
      unsigned v2 = ((const unsigned*)(xrs + (size_t)__builtin_amdgcn_readlane(my, e + 2)))[lane];
      unsigned v3 = ((const unsigned*)(xrs + (size_t)__builtin_amdgcn_readlane(my, e + 3)))[lane];
      unsigned v4 = ((const unsigned*)(xrs + (size_t)__builtin_amdgcn_readlane(my, e + 4)))[lane];
      unsigned v5 = ((const unsigned*)(xrs + (size_t)__builtin_amdgcn_readlane(my, e + 5)))[lane];
      unsigned v6 = ((const unsigned*)(xrs + (size_t)__builtin_amdgcn_readlane(my, e + 6)))[lane];
      unsigned v7 = ((const unsigned*)(xrs + (size_t)__builtin_amdgcn_readlane(my, e + 7)))[lane];
      ax += bf2f(v0 & 0xffffu); ay += bf2f(v0 >> 16);
      ax += bf2f(v1 & 0xffffu); ay += bf2f(v1 >> 16);
      ax += bf2f(v2 & 0xffffu); ay += bf2f(v2 >> 16);
      ax += bf2f(v3 & 0xffffu); ay += bf2f(v3 >> 16);
      ax += bf2f(v4 & 0xffffu); ay += bf2f(v4 >> 16);
      ax += bf2f(v5 & 0xffffu); ay += bf2f(v5 >> 16);
      ax += bf2f(v6 & 0xffffu); ay += bf2f(v6 >> 16);
      ax += bf2f(v7 & 0xffffu); ay += bf2f(v7 >> 16);
    }
    for (; e < cnt; ++e) {
      unsigned v = ((const unsigned*)(xrs + (size_t)__builtin_amdgcn_readlane(my, e)))[lane];
      ax += bf2f(v & 0xffffu); ay += bf2f(v >> 16);
    }
  }

  float2 bb = ((const float2*)bias)[lane];
  ax = fmaxf(ax + bb.x, 0.f);
  ay = fmaxf(ay + bb.y, 0.f);
  ((unsigned*)(hout + (size_t)node * F))[lane] = f2bf(ax) | (f2bf(ay) << 16);
}

// ==================== mean-pool (+final fc) =================================
__global__ __launch_bounds__(256)
void k_colsum(const ushort* __restrict__ h2, float* __restrict__ pooled) {
  __shared__ float red[4][128];
  const int j = threadIdx.x & 63;
  const int wv = threadIdx.x >> 6;
  float sx = 0.f, sy = 0.f;
  for (int r0 = blockIdx.x * 16 + wv * 4; r0 < NNODES; r0 += gridDim.x * 16) {
    const unsigned* p = (const unsigned*)h2 + (size_t)r0 * 64 + j;
    unsigned v0 = p[0];
    unsigned v1 = (r0 + 1 < NNODES) ? p[64] : 0;
    unsigned v2 = (r0 + 2 < NNODES) ? p[128] : 0;
    unsigned v3 = (r0 + 3 < NNODES) ? p[192] : 0;
    sx += bf2f(v0 & 0xffffu) + bf2f(v1 & 0xffffu) +
          bf2f(v2 & 0xffffu) + bf2f(v3 & 0xffffu);
    sy += bf2f(v0 >> 16) + bf2f(v1 >> 16) + bf2f(v2 >> 16) + bf2f(v3 >> 16);
  }
  red[wv][2 * j] = sx;
  red[wv][2 * j + 1] = sy;
  __syncthreads();
  if (threadIdx.x < 128) {
    float s = red[0][threadIdx.x] + red[1][threadIdx.x] +
              red[2][threadIdx.x] + red[3][threadIdx.x];
    atomicAdd(&pooled[threadIdx.x], s);
  }
}

__global__ __launch_bounds__(128)
void final_fc(const float* __restrict__ pooled, const float* __restrict__ fc_w,
              const float* __restrict__ fc_b, float* __restrict__ out) {
  __shared__ float s[F];
  int t = threadIdx.x;
  s[t] = pooled[t] * (1.0f / (float)NNODES) * fc_w[t];
  __syncthreads();
  if (t == 0) {
    float v = 0.f;
    for (int i = 0; i < F; ++i) v += s[i];
    v += fc_b[0];
    out[0] = 1.f / (1.f + expf(-v));
  }
}

// ============================================================================
extern "C" void kernel_launch(void* const* d_in, const int* in_sizes, int n_in,
                              void* d_out, int out_size, void* d_ws, size_t ws_size,
                              hipStream_t stream) {
  const float* in_feat = (const float*)d_in[0];
  const float* W1      = (const float*)d_in[1];
  const float* W1s     = (const float*)d_in[2];
  const float* b1      = (const float*)d_in[3];
  const float* W2      = (const float*)d_in[4];
  const float* W2s     = (const float*)d_in[5];
  const float* b2      = (const float*)d_in[6];
  const float* fcw     = (const float*)d_in[7];
  const float* fcb     = (const float*)d_in[8];
  const int*   src     = (const int*)d_in[9];
  const int*   dst     = (const int*)d_in[10];
  const int*   et      = (const int*)d_in[11];
  float* out = (float*)d_out;

  // Workspace (~165 MB)
  ushort* xrs   = (ushort*)d_ws;                     // [50000][1152]
  ushort* feat0 = xrs + (size_t)NNODES * NOUT;       // [50000][128]
  ushort* h1    = feat0 + (size_t)NNODES * F;        // [50000][128]
  ushort* h2    = h1 + (size_t)NNODES * F;           // [50000][128]
  ushort* Wt1   = h2 + (size_t)NNODES * F;           // [1152][128]
  ushort* Wt2   = Wt1 + (size_t)NOUT * F;            // [1152][128]
  float* pooled = (float*)(Wt2 + (size_t)NOUT * F);  // [128] + pad
  int*   rowptr = (int*)(pooled + 256);              // [NNODES+1]
  int*   bcnt   = rowptr + NNODES + 2;               // [NBKT]
  int*   bbase  = bcnt + NBKT;                       // [NBKT]
  int*   bcur   = bbase + NBKT;                      // [NBKT]
  int*   ebuf   = bcur + NBKT + 1;                   // [NEDGES]
  int*   edata  = ebuf + NEDGES;                     // [NEDGES]

  hipMemsetAsync(bcnt, 0, NBKT * sizeof(int), stream);
  hipMemsetAsync(pooled, 0, 128 * sizeof(float), stream);

  // CSR via two-level counting sort
  k_chist<<<196, 256, 0, stream>>>(dst, bcnt);
  k_cscan<<<1, 128, 0, stream>>>(bcnt, bbase, bcur, rowptr);
  k_cscatter<<<196, 256, 0, stream>>>(src, dst, et, bcur, ebuf);
  k_fsort<<<NBKT, 256, 0, stream>>>(ebuf, bbase, bcnt, rowptr, edata);

  // bf16 conversions / weight prep
  k_cvt<<<(NNODES * F / 2 + 255) / 256, 256, 0, stream>>>(in_feat, feat0, NNODES * F / 2);
  k_prepw<<<(NOUT * F + 255) / 256, 256, 0, stream>>>(W1, W1s, Wt1);
  k_prepw<<<(NOUT * F + 255) / 256, 256, 0, stream>>>(W2, W2s, Wt2);

  dim3 gemmGrid((NNODES + 127) / 128, 9);              // 391 x 9
  const int aggBlocks = (NNODES * 64 + 255) / 256;     // 12500

  // Layer 1: transform then aggregate
  gemm_xrs<<<gemmGrid, 256, 0, stream>>>(feat0, Wt1, xrs);
  k_aggregate<<<aggBlocks, 256, 0, stream>>>(xrs, rowptr, edata, b1, h1);
  // Layer 2
  gemm_xrs<<<gemmGrid, 256, 0, stream>>>(h1, Wt2, xrs);
  k_aggregate<<<aggBlocks, 256, 0, stream>>>(xrs, rowptr, edata, b2, h2);

  // Mean-pool + fc + sigmoid
  k_colsum<<<784, 256, 0, stream>>>(h2, pooled);
  final_fc<<<1, 128, 0, stream>>>(pooled, fcw, fcb, out);
}